// Round 1
// baseline (603.662 us; speedup 1.0000x reference)
//
#include <hip/hip_runtime.h>
#include <math.h>

#define Bc 4
#define Cc 128
#define Hc 64
#define Wc 64
#define Lc 4096          // H*W
#define Ec 256
#define Nc 16
#define Rc 8
#define Kc 4
#define ROWS (Bc*Lc)     // 16384
#define EPSc 1e-5f
#define SLOPE 0.01f

#define NCH 64           // chunks per sequence
#define Tc 64            // chunk length (NCH*Tc == Lc)

// ---------------------------------------------------------------------------
// Transpose x (B,C,L) -> xblc (B,L,C)
__global__ void transpose_in(const float* __restrict__ x, float* __restrict__ xblc) {
    __shared__ float tile[32][33];
    int b = blockIdx.z;
    int l0 = blockIdx.x * 32, c0 = blockIdx.y * 32;
    int tx = threadIdx.x, ty = threadIdx.y;
    tile[ty][tx] = x[((size_t)(b * Cc + c0 + ty)) * Lc + l0 + tx];
    __syncthreads();
    xblc[((size_t)(b * Lc + l0 + ty)) * Cc + c0 + tx] = tile[tx][ty];
}

// Final: out(B,C,L) = x(B,C,L) + s2(B,L,C) transposed
__global__ void final_out(const float* __restrict__ s2, const float* __restrict__ x,
                          float* __restrict__ out) {
    __shared__ float tile[32][33];
    int b = blockIdx.z;
    int l0 = blockIdx.x * 32, c0 = blockIdx.y * 32;
    int tx = threadIdx.x, ty = threadIdx.y;
    tile[ty][tx] = s2[((size_t)(b * Lc + l0 + ty)) * Cc + c0 + tx];
    __syncthreads();
    size_t oidx = ((size_t)(b * Cc + c0 + ty)) * Lc + l0 + tx;
    out[oidx] = x[oidx] + tile[tx][ty];
}

// ---------------------------------------------------------------------------
// BN stats: partial sums per 64-row slab, deterministic finalize
__global__ void bn_stats_partial(const float* __restrict__ xblc, float* __restrict__ part) {
    int c = threadIdx.x;              // 128
    int r0 = blockIdx.x * 64;         // 256 blocks
    float s = 0.f, s2 = 0.f;
    for (int r = 0; r < 64; r++) {
        float v = xblc[(size_t)(r0 + r) * Cc + c];
        s += v; s2 += v * v;
    }
    part[(size_t)blockIdx.x * 256 + c]       = s;
    part[(size_t)blockIdx.x * 256 + 128 + c] = s2;
}

__global__ void bn_stats_final(const float* __restrict__ part, float* __restrict__ sums) {
    int c = threadIdx.x;              // 128 threads, 1 block
    float s = 0.f, s2 = 0.f;
    for (int p = 0; p < 256; p++) {
        s  += part[(size_t)p * 256 + c];
        s2 += part[(size_t)p * 256 + 128 + c];
    }
    sums[c] = s;
    sums[128 + c] = s2;
}

// ---------------------------------------------------------------------------
// BN-normalize + leaky relu -> u ; LayerNorm(u) -> un (written over s_in)
__global__ void bn_ln(const float* __restrict__ xin, const float* __restrict__ sums,
                      const float* __restrict__ bng, const float* __restrict__ bnb,
                      const float* __restrict__ lng, const float* __restrict__ lnb,
                      float* __restrict__ u, float* __restrict__ un) {
    int row = blockIdx.x;
    int c = threadIdx.x;              // 128
    float v = xin[(size_t)row * Cc + c];
    float mean = sums[c] * (1.f / (float)ROWS);
    float var  = sums[128 + c] * (1.f / (float)ROWS) - mean * mean;
    float xn = (v - mean) * rsqrtf(var + EPSc) * bng[c] + bnb[c];
    xn = (xn < 0.f) ? SLOPE * xn : xn;
    __shared__ float red[128];
    __shared__ float red2[128];
    red[c] = xn; red2[c] = xn * xn;
    __syncthreads();
    for (int s = 64; s > 0; s >>= 1) {
        if (c < s) { red[c] += red[c + s]; red2[c] += red2[c + s]; }
        __syncthreads();
    }
    float m2 = red[0] * (1.f / 128.f);
    float v2 = red2[0] * (1.f / 128.f) - m2 * m2;
    float rstd = rsqrtf(v2 + EPSc);
    u[(size_t)row * Cc + c]  = xn;
    un[(size_t)row * Cc + c] = (xn - m2) * rstd * lng[c] + lnb[c];
}

// ---------------------------------------------------------------------------
// Generic tiled fp32 GEMM: out[M,N] = A[M,K] @ B[K,N] (+ add[M,N])
__global__ __launch_bounds__(256) void gemm_kernel(
        const float* __restrict__ A, int lda,
        const float* __restrict__ Bm, int ldb,
        const float* __restrict__ add, int ldadd,
        float* __restrict__ Cout, int ldc,
        int M, int N, int K) {
    __shared__ float As[16][65];
    __shared__ float Bs[16][65];
    int tid = threadIdx.x;
    int tx = tid & 15, ty = tid >> 4;
    int row0 = blockIdx.x * 64, col0 = blockIdx.y * 64;
    float acc[4][4] = {};
    for (int k0 = 0; k0 < K; k0 += 16) {
        #pragma unroll
        for (int i = 0; i < 4; i++) {
            int idx = tid + i * 256;
            int m = idx >> 4, kk = idx & 15;
            As[kk][m] = A[(size_t)(row0 + m) * lda + k0 + kk];
        }
        #pragma unroll
        for (int i = 0; i < 4; i++) {
            int idx = tid + i * 256;
            int n = idx & 63, kk = idx >> 6;
            int col = col0 + n;
            Bs[kk][n] = (col < N) ? Bm[(size_t)(k0 + kk) * ldb + col] : 0.f;
        }
        __syncthreads();
        #pragma unroll
        for (int kk = 0; kk < 16; kk++) {
            float a[4], bb[4];
            #pragma unroll
            for (int i = 0; i < 4; i++) a[i] = As[kk][ty * 4 + i];
            #pragma unroll
            for (int j = 0; j < 4; j++) bb[j] = Bs[kk][tx * 4 + j];
            #pragma unroll
            for (int i = 0; i < 4; i++)
                #pragma unroll
                for (int j = 0; j < 4; j++)
                    acc[i][j] += a[i] * bb[j];
        }
        __syncthreads();
    }
    #pragma unroll
    for (int i = 0; i < 4; i++) {
        int r = row0 + ty * 4 + i;
        #pragma unroll
        for (int j = 0; j < 4; j++) {
            int c = col0 + tx * 4 + j;
            if (c < N) {
                float v = acc[i][j];
                if (add) v += add[(size_t)r * ldadd + c];
                Cout[(size_t)r * ldc + c] = v;
            }
        }
    }
}

// ---------------------------------------------------------------------------
// depthwise causal conv (K=4) + bias + SiLU.  xz row stride 512, xm = cols [0,256)
__global__ void conv_silu(const float* __restrict__ xz, const float* __restrict__ cw,
                          const float* __restrict__ cb, float* __restrict__ xconv) {
    int row = blockIdx.x;             // b*L + l
    int e = threadIdx.x;              // 256
    int l = row & (Lc - 1);
    float s = cb[e];
    #pragma unroll
    for (int k = 0; k < Kc; k++) {
        int ls = l - (Kc - 1) + k;
        if (ls >= 0)
            s += xz[(size_t)(row - (Kc - 1) + k) * 512 + e] * cw[e * Kc + k];
    }
    float sig = 1.f / (1.f + __expf(-s));
    xconv[(size_t)row * Ec + e] = s * sig;
}

// dt = softplus(dbl[:, :8] @ W_dt + b_dt)
__global__ void dt_kernel(const float* __restrict__ dbl, const float* __restrict__ Wdt,
                          const float* __restrict__ bdt, float* __restrict__ dtb) {
    int row = blockIdx.x;
    int e = threadIdx.x;              // 256
    __shared__ float dsh[8];
    if (e < 8) dsh[e] = dbl[(size_t)row * 40 + e];
    __syncthreads();
    float s = bdt[e];
    #pragma unroll
    for (int r = 0; r < Rc; r++) s += dsh[r] * Wdt[r * Ec + e];
    float sp = fmaxf(s, 0.f) + log1pf(__expf(-fabsf(s)));
    dtb[(size_t)row * Ec + e] = sp;
}

// ---------------------------------------------------------------------------
// Chunked selective scan.
// phase1: per (b, chunk): P = prod(dA), F = from-zero final state
__global__ __launch_bounds__(256) void scan_phase1(
        const float* __restrict__ dtb, const float* __restrict__ xconv,
        const float* __restrict__ dbl, const float* __restrict__ Alog,
        float* __restrict__ P, float* __restrict__ F) {
    int blk = blockIdx.x;             // b*NCH + j
    int b = blk / NCH, j = blk % NCH;
    int e = threadIdx.x;
    __shared__ float Bsh[Tc][Nc];
    for (int idx = threadIdx.x; idx < Tc * Nc; idx += 256) {
        int t = idx / Nc, n = idx % Nc;
        int row = b * Lc + j * Tc + t;
        Bsh[t][n] = dbl[(size_t)row * 40 + 8 + n];
    }
    __syncthreads();
    float Aen[Nc];
    #pragma unroll
    for (int n = 0; n < Nc; n++) Aen[n] = -__expf(Alog[e * Nc + n]);
    float Pv[Nc], Fv[Nc];
    #pragma unroll
    for (int n = 0; n < Nc; n++) { Pv[n] = 1.f; Fv[n] = 0.f; }
    int base_row = b * Lc + j * Tc;
    for (int t = 0; t < Tc; t++) {
        int row = base_row + t;
        float dtv = dtb[(size_t)row * Ec + e];
        float xv  = xconv[(size_t)row * Ec + e];
        float dx = dtv * xv;
        #pragma unroll
        for (int n = 0; n < Nc; n++) {
            float dA = __expf(dtv * Aen[n]);
            Pv[n] *= dA;
            Fv[n] = dA * Fv[n] + dx * Bsh[t][n];
        }
    }
    size_t o = ((size_t)blk * Ec + e) * Nc;
    #pragma unroll
    for (int n = 0; n < Nc; n++) { P[o + n] = Pv[n]; F[o + n] = Fv[n]; }
}

// phase2: scan across chunks; Hinit[b,j,:,:] = state entering chunk j
__global__ void scan_phase2(const float* __restrict__ P, const float* __restrict__ F,
                            float* __restrict__ Hinit) {
    int idx = blockIdx.x * blockDim.x + threadIdx.x;   // B*E*N = 16384
    int b = idx / (Ec * Nc);
    int r = idx % (Ec * Nc);
    float h = 0.f;
    for (int j = 0; j < NCH; j++) {
        size_t o = (size_t)(b * NCH + j) * (Ec * Nc) + r;
        Hinit[o] = h;
        h = P[o] * h + F[o];
    }
}

// phase3: recompute in-chunk scan from Hinit, emit y (gated) into xz xm-region
__global__ __launch_bounds__(256) void scan_phase3(
        const float* __restrict__ dtb, const float* __restrict__ xconv,
        const float* __restrict__ dbl, const float* __restrict__ Alog,
        const float* __restrict__ Dpv, const float* __restrict__ Hinit,
        float* xz) {
    int blk = blockIdx.x;
    int b = blk / NCH, j = blk % NCH;
    int e = threadIdx.x;
    __shared__ float Bsh[Tc][Nc];
    __shared__ float Csh[Tc][Nc];
    for (int idx = threadIdx.x; idx < Tc * Nc; idx += 256) {
        int t = idx / Nc, n = idx % Nc;
        int row = b * Lc + j * Tc + t;
        Bsh[t][n] = dbl[(size_t)row * 40 + 8 + n];
        Csh[t][n] = dbl[(size_t)row * 40 + 24 + n];
    }
    __syncthreads();
    float Aen[Nc];
    #pragma unroll
    for (int n = 0; n < Nc; n++) Aen[n] = -__expf(Alog[e * Nc + n]);
    float h[Nc];
    size_t o = ((size_t)blk * Ec + e) * Nc;
    #pragma unroll
    for (int n = 0; n < Nc; n++) h[n] = Hinit[o + n];
    float dp = Dpv[e];
    int base_row = b * Lc + j * Tc;
    for (int t = 0; t < Tc; t++) {
        int row = base_row + t;
        float dtv = dtb[(size_t)row * Ec + e];
        float xv  = xconv[(size_t)row * Ec + e];
        float dx = dtv * xv;
        float acc = 0.f;
        #pragma unroll
        for (int n = 0; n < Nc; n++) {
            float dA = __expf(dtv * Aen[n]);
            h[n] = dA * h[n] + dx * Bsh[t][n];
            acc += h[n] * Csh[t][n];
        }
        float yv = acc + dp * xv;
        float zv = xz[(size_t)row * 512 + 256 + e];
        float sig = 1.f / (1.f + __expf(-zv));
        xz[(size_t)row * 512 + e] = yv * (zv * sig);
    }
}

// ---------------------------------------------------------------------------
extern "C" void kernel_launch(void* const* d_in, const int* in_sizes, int n_in,
                              void* d_out, int out_size, void* d_ws, size_t ws_size,
                              hipStream_t stream) {
    const float* x        = (const float*)d_in[0];
    const float* bn_gamma = (const float*)d_in[1];
    const float* bn_beta  = (const float*)d_in[2];
    const float* ln_gamma = (const float*)d_in[3];
    const float* ln_beta  = (const float*)d_in[4];
    const float* W_in     = (const float*)d_in[5];
    const float* conv_w   = (const float*)d_in[6];
    const float* conv_b   = (const float*)d_in[7];
    const float* W_xp     = (const float*)d_in[8];
    const float* W_dt     = (const float*)d_in[9];
    const float* b_dt     = (const float*)d_in[10];
    const float* A_log    = (const float*)d_in[11];
    const float* Dp       = (const float*)d_in[12];
    const float* W_out    = (const float*)d_in[13];
    float* out = (float*)d_out;

    char* ws = (char*)d_ws;
    size_t off = 0;
    auto alloc = [&](size_t nfloats) {
        float* p = (float*)(ws + off);
        off += ((nfloats * sizeof(float) + 255) / 256) * 256;
        return p;
    };
    float* xblc  = alloc((size_t)ROWS * Cc);       // 8 MB
    float* buf2  = alloc((size_t)ROWS * Cc);       // 8 MB
    float* u     = alloc((size_t)ROWS * Cc);       // 8 MB
    float* xz    = alloc((size_t)ROWS * 512);      // 32 MB  (xm | z; y overwrites xm)
    float* xconv = alloc((size_t)ROWS * Ec);       // 16 MB
    float* dbl   = alloc((size_t)ROWS * 40);       // 2.6 MB
    float* dtb   = alloc((size_t)ROWS * Ec);       // 16 MB
    float* P     = alloc((size_t)Bc * NCH * Ec * Nc);  // 4 MB
    float* F     = alloc((size_t)Bc * NCH * Ec * Nc);  // 4 MB
    float* Hin   = alloc((size_t)Bc * NCH * Ec * Nc);  // 4 MB
    float* part  = alloc(256 * 256);               // BN partials
    float* sums  = alloc(256);

    transpose_in<<<dim3(Lc / 32, Cc / 32, Bc), dim3(32, 32), 0, stream>>>(x, xblc);

    for (int i = 0; i < 2; i++) {
        float* s_in  = (i == 0) ? xblc : buf2;
        float* s_out = (i == 0) ? buf2 : xblc;

        bn_stats_partial<<<256, 128, 0, stream>>>(s_in, part);
        bn_stats_final<<<1, 128, 0, stream>>>(part, sums);
        bn_ln<<<ROWS, 128, 0, stream>>>(s_in, sums,
                                        bn_gamma + i * Cc, bn_beta + i * Cc,
                                        ln_gamma + i * Cc, ln_beta + i * Cc,
                                        u, s_in /* un in place */);
        // xz = un @ W_in   (16384 x 512, K=128)
        gemm_kernel<<<dim3(ROWS / 64, 8), 256, 0, stream>>>(
            s_in, Cc, W_in + (size_t)i * Cc * 2 * Ec, 2 * Ec,
            nullptr, 0, xz, 512, ROWS, 512, Cc);
        conv_silu<<<ROWS, Ec, 0, stream>>>(xz, conv_w + i * Ec * Kc, conv_b + i * Ec, xconv);
        // dbl = xconv @ W_xp  (16384 x 40, K=256)
        gemm_kernel<<<dim3(ROWS / 64, 1), 256, 0, stream>>>(
            xconv, Ec, W_xp + (size_t)i * Ec * 40, 40,
            nullptr, 0, dbl, 40, ROWS, 40, Ec);
        dt_kernel<<<ROWS, Ec, 0, stream>>>(dbl, W_dt + i * Rc * Ec, b_dt + i * Ec, dtb);
        scan_phase1<<<Bc * NCH, Ec, 0, stream>>>(dtb, xconv, dbl,
                                                 A_log + i * Ec * Nc, P, F);
        scan_phase2<<<Bc * Ec * Nc / 256, 256, 0, stream>>>(P, F, Hin);
        scan_phase3<<<Bc * NCH, Ec, 0, stream>>>(dtb, xconv, dbl,
                                                 A_log + i * Ec * Nc, Dp + i * Ec, Hin, xz);
        // s_out = u + y @ W_out  (16384 x 128, K=256); y lives in xz cols [0,256)
        gemm_kernel<<<dim3(ROWS / 64, 2), 256, 0, stream>>>(
            xz, 512, W_out + (size_t)i * Ec * Cc, Cc,
            u, Cc, s_out, Cc, ROWS, Cc, Ec);
    }

    final_out<<<dim3(Lc / 32, Cc / 32, Bc), dim3(32, 32), 0, stream>>>(xblc, x, out);
}

// Round 2
// 502.703 us; speedup vs baseline: 1.2008x; 1.2008x over previous
//
#include <hip/hip_runtime.h>
#include <math.h>

#define Bc 4
#define Cc 128
#define Lc 4096          // H*W
#define Ec 256
#define Nc 16
#define Rc 8
#define Kc 4
#define ROWS (Bc*Lc)     // 16384
#define EPSc 1e-5f
#define SLOPE 0.01f

#define NCH 128          // chunks per sequence
#define Tc 32            // chunk length (NCH*Tc == Lc)

typedef __attribute__((ext_vector_type(8))) short bf16x8;
typedef __attribute__((ext_vector_type(4))) float f32x4;

// RNE float->bf16, packed pair into one u32 (lo = x, hi = y)
__device__ inline unsigned pack_bf16_2(float x, float y) {
    unsigned bx = __float_as_uint(x);
    unsigned by = __float_as_uint(y);
    bx = (bx + 0x7FFFu + ((bx >> 16) & 1u)) >> 16;
    by = (by + 0x7FFFu + ((by >> 16) & 1u)) & 0xFFFF0000u;
    return bx | by;
}

// ---------------------------------------------------------------------------
// Transpose x (B,C,L) -> xblc (B,L,C)
__global__ void transpose_in(const float* __restrict__ x, float* __restrict__ xblc) {
    __shared__ float tile[32][33];
    int b = blockIdx.z;
    int l0 = blockIdx.x * 32, c0 = blockIdx.y * 32;
    int tx = threadIdx.x, ty = threadIdx.y;
    tile[ty][tx] = x[((size_t)(b * Cc + c0 + ty)) * Lc + l0 + tx];
    __syncthreads();
    xblc[((size_t)(b * Lc + l0 + ty)) * Cc + c0 + tx] = tile[tx][ty];
}

// Final: out(B,C,L) = x(B,C,L) + s2(B,L,C) transposed
__global__ void final_out(const float* __restrict__ s2, const float* __restrict__ x,
                          float* __restrict__ out) {
    __shared__ float tile[32][33];
    int b = blockIdx.z;
    int l0 = blockIdx.x * 32, c0 = blockIdx.y * 32;
    int tx = threadIdx.x, ty = threadIdx.y;
    tile[ty][tx] = s2[((size_t)(b * Lc + l0 + ty)) * Cc + c0 + tx];
    __syncthreads();
    size_t oidx = ((size_t)(b * Cc + c0 + ty)) * Lc + l0 + tx;
    out[oidx] = x[oidx] + tile[tx][ty];
}

// ---------------------------------------------------------------------------
// Weight transpose+convert: W[2][K][N] fp32 -> Wt[2][NPAD][K] bf16 (zero-pad n)
__global__ void wt_convert(const float* __restrict__ W, unsigned short* __restrict__ Wt,
                           int K, int N, int NPAD) {
    int idx = blockIdx.x * 256 + threadIdx.x;   // over 2*NPAD*K
    int k = idx % K;
    int n = (idx / K) % NPAD;
    int i = idx / (K * NPAD);
    float v = (n < N) ? W[(size_t)i * K * N + (size_t)k * N + n] : 0.f;
    unsigned b = __float_as_uint(v);
    Wt[idx] = (unsigned short)((b + 0x7FFFu + ((b >> 16) & 1u)) >> 16);
}

// ---------------------------------------------------------------------------
// BN stats: partial sums per 64-row slab, deterministic finalize
__global__ void bn_stats_partial(const float* __restrict__ xblc, float* __restrict__ part) {
    int c = threadIdx.x;              // 128
    int r0 = blockIdx.x * 64;         // 256 blocks
    float s = 0.f, s2 = 0.f;
    for (int r = 0; r < 64; r++) {
        float v = xblc[(size_t)(r0 + r) * Cc + c];
        s += v; s2 += v * v;
    }
    part[(size_t)blockIdx.x * 256 + c]       = s;
    part[(size_t)blockIdx.x * 256 + 128 + c] = s2;
}

__global__ void bn_stats_final(const float* __restrict__ part, float* __restrict__ sums) {
    int c = threadIdx.x;              // 128 threads, 1 block
    float s = 0.f, s2 = 0.f;
    for (int p = 0; p < 256; p++) {
        s  += part[(size_t)p * 256 + c];
        s2 += part[(size_t)p * 256 + 128 + c];
    }
    sums[c] = s;
    sums[128 + c] = s2;
}

// ---------------------------------------------------------------------------
// BN-normalize + leaky relu -> u ; LayerNorm(u) -> un (written over s_in)
__global__ void bn_ln(const float* __restrict__ xin, const float* __restrict__ sums,
                      const float* __restrict__ bng, const float* __restrict__ bnb,
                      const float* __restrict__ lng, const float* __restrict__ lnb,
                      float* __restrict__ u, float* __restrict__ un) {
    int row = blockIdx.x;
    int c = threadIdx.x;              // 128
    float v = xin[(size_t)row * Cc + c];
    float mean = sums[c] * (1.f / (float)ROWS);
    float var  = sums[128 + c] * (1.f / (float)ROWS) - mean * mean;
    float xn = (v - mean) * rsqrtf(var + EPSc) * bng[c] + bnb[c];
    xn = (xn < 0.f) ? SLOPE * xn : xn;
    __shared__ float red[128];
    __shared__ float red2[128];
    red[c] = xn; red2[c] = xn * xn;
    __syncthreads();
    for (int s = 64; s > 0; s >>= 1) {
        if (c < s) { red[c] += red[c + s]; red2[c] += red2[c + s]; }
        __syncthreads();
    }
    float m2 = red[0] * (1.f / 128.f);
    float v2 = red2[0] * (1.f / 128.f) - m2 * m2;
    float rstd = rsqrtf(v2 + EPSc);
    u[(size_t)row * Cc + c]  = xn;
    un[(size_t)row * Cc + c] = (xn - m2) * rstd * lng[c] + lnb[c];
}

// ---------------------------------------------------------------------------
// MFMA bf16 GEMM (LDS-free): Cout[M,N] = A[M,K](fp32) @ Wt[N][K](bf16)^T (+ add)
// Block = 4 waves, 64x64 output tile. Wave w: rows [w*16, w*16+16), all 64 cols.
// A-frag:  lane L holds A[m = L&15][k = (L>>4)*8 + j]  (m89-verified mapping)
// B-frag:  lane L holds B[k = (L>>4)*8 + j][n = L&15]  == Wt[n][k]
// D:       lane L, reg r -> row = (L>>4)*4 + r, col = L&15
template<int K>
__global__ __launch_bounds__(256) void mfma_gemm(
        const float* __restrict__ A, int lda,
        const unsigned short* __restrict__ Wt,
        const float* __restrict__ add, int ldadd,
        float* __restrict__ Cout, int ldc, int N) {
    int tid = threadIdx.x;
    int wave = tid >> 6, lane = tid & 63;
    int quad = lane >> 4, l16 = lane & 15;
    int row0 = blockIdx.y * 64 + wave * 16;
    int col0 = blockIdx.x * 64;

    f32x4 acc[4] = {f32x4{0,0,0,0}, f32x4{0,0,0,0}, f32x4{0,0,0,0}, f32x4{0,0,0,0}};

    const float* arow = A + (size_t)(row0 + l16) * lda + quad * 8;
    const unsigned short* bbase = Wt + (size_t)(col0 + l16) * K + quad * 8;

    #pragma unroll
    for (int s = 0; s < K / 32; s++) {
        float4 a0 = *(const float4*)(arow + s * 32);
        float4 a1 = *(const float4*)(arow + s * 32 + 4);
        union { unsigned u[4]; bf16x8 v; } af;
        af.u[0] = pack_bf16_2(a0.x, a0.y);
        af.u[1] = pack_bf16_2(a0.z, a0.w);
        af.u[2] = pack_bf16_2(a1.x, a1.y);
        af.u[3] = pack_bf16_2(a1.z, a1.w);
        #pragma unroll
        for (int c = 0; c < 4; c++) {
            bf16x8 bf = *(const bf16x8*)(bbase + (size_t)c * 16 * K + s * 32);
            acc[c] = __builtin_amdgcn_mfma_f32_16x16x32_bf16(af.v, bf, acc[c], 0, 0, 0);
        }
    }

    #pragma unroll
    for (int c = 0; c < 4; c++) {
        int col = col0 + c * 16 + l16;
        if (col < N) {
            #pragma unroll
            for (int r = 0; r < 4; r++) {
                int row = row0 + quad * 4 + r;
                float v = acc[c][r];
                if (add) v += add[(size_t)row * ldadd + col];
                Cout[(size_t)row * ldc + col] = v;
            }
        }
    }
}

// ---------------------------------------------------------------------------
// depthwise causal conv (K=4) + bias + SiLU.  xz row stride 512, xm = cols [0,256)
__global__ void conv_silu(const float* __restrict__ xz, const float* __restrict__ cw,
                          const float* __restrict__ cb, float* __restrict__ xconv) {
    int row = blockIdx.x;             // b*L + l
    int e = threadIdx.x;              // 256
    int l = row & (Lc - 1);
    float s = cb[e];
    #pragma unroll
    for (int k = 0; k < Kc; k++) {
        int ls = l - (Kc - 1) + k;
        if (ls >= 0)
            s += xz[(size_t)(row - (Kc - 1) + k) * 512 + e] * cw[e * Kc + k];
    }
    float sig = 1.f / (1.f + __expf(-s));
    xconv[(size_t)row * Ec + e] = s * sig;
}

__device__ inline float softplusf(float s) {
    return fmaxf(s, 0.f) + log1pf(__expf(-fabsf(s)));
}

// ---------------------------------------------------------------------------
// Chunked selective scan; dt computed in-kernel (fused dt_kernel).
// phase1: per (b, chunk): P = prod(dA), F = from-zero final state
__global__ __launch_bounds__(256) void scan_phase1(
        const float* __restrict__ xconv, const float* __restrict__ dbl,
        const float* __restrict__ Alog,
        const float* __restrict__ Wdt, const float* __restrict__ bdt,
        float* __restrict__ P, float* __restrict__ F) {
    int blk = blockIdx.x;             // b*NCH + j
    int b = blk >> 7, j = blk & (NCH - 1);
    int e = threadIdx.x;
    __shared__ float Bsh[Tc][Nc];
    __shared__ float Dsh[Tc][Rc];
    int base_row = b * Lc + j * Tc;
    for (int idx = threadIdx.x; idx < Tc * Nc; idx += 256) {
        int t = idx >> 4, n = idx & 15;
        Bsh[t][n] = dbl[(size_t)(base_row + t) * 40 + 8 + n];
    }
    for (int idx = threadIdx.x; idx < Tc * Rc; idx += 256) {
        int t = idx >> 3, r = idx & 7;
        Dsh[t][r] = dbl[(size_t)(base_row + t) * 40 + r];
    }
    __syncthreads();
    float Aen[Nc];
    #pragma unroll
    for (int n = 0; n < Nc; n++) Aen[n] = -__expf(Alog[e * Nc + n]);
    float wdt[Rc];
    #pragma unroll
    for (int r = 0; r < Rc; r++) wdt[r] = Wdt[r * Ec + e];
    float bd = bdt[e];
    float Pv[Nc], Fv[Nc];
    #pragma unroll
    for (int n = 0; n < Nc; n++) { Pv[n] = 1.f; Fv[n] = 0.f; }
    for (int t = 0; t < Tc; t++) {
        float s = bd;
        #pragma unroll
        for (int r = 0; r < Rc; r++) s += Dsh[t][r] * wdt[r];
        float dtv = softplusf(s);
        float xv = xconv[(size_t)(base_row + t) * Ec + e];
        float dx = dtv * xv;
        #pragma unroll
        for (int n = 0; n < Nc; n++) {
            float dA = __expf(dtv * Aen[n]);
            Pv[n] *= dA;
            Fv[n] = dA * Fv[n] + dx * Bsh[t][n];
        }
    }
    size_t o = ((size_t)blk * Ec + e) * Nc;
    #pragma unroll
    for (int n = 0; n < Nc; n++) { P[o + n] = Pv[n]; F[o + n] = Fv[n]; }
}

// phase2: scan across chunks; Hinit written IN-PLACE over P (read p,f before store)
__global__ void scan_phase2(float* P, const float* F) {
    int idx = blockIdx.x * blockDim.x + threadIdx.x;   // B*E*N = 16384
    int b = idx / (Ec * Nc);
    int r = idx % (Ec * Nc);
    float h = 0.f;
    for (int j = 0; j < NCH; j++) {
        size_t o = (size_t)(b * NCH + j) * (Ec * Nc) + r;
        float p = P[o];
        float f = F[o];
        P[o] = h;               // Hinit
        h = p * h + f;
    }
}

// phase3: recompute in-chunk scan from Hinit(=P), emit gated y into xz xm-region
__global__ __launch_bounds__(256) void scan_phase3(
        const float* __restrict__ xconv, const float* __restrict__ dbl,
        const float* __restrict__ Alog,
        const float* __restrict__ Wdt, const float* __restrict__ bdt,
        const float* __restrict__ Dpv, const float* __restrict__ Hinit,
        float* xz) {
    int blk = blockIdx.x;
    int b = blk >> 7, j = blk & (NCH - 1);
    int e = threadIdx.x;
    __shared__ float Bsh[Tc][Nc];
    __shared__ float Csh[Tc][Nc];
    __shared__ float Dsh[Tc][Rc];
    int base_row = b * Lc + j * Tc;
    for (int idx = threadIdx.x; idx < Tc * Nc; idx += 256) {
        int t = idx >> 4, n = idx & 15;
        Bsh[t][n] = dbl[(size_t)(base_row + t) * 40 + 8 + n];
        Csh[t][n] = dbl[(size_t)(base_row + t) * 40 + 24 + n];
    }
    for (int idx = threadIdx.x; idx < Tc * Rc; idx += 256) {
        int t = idx >> 3, r = idx & 7;
        Dsh[t][r] = dbl[(size_t)(base_row + t) * 40 + r];
    }
    __syncthreads();
    float Aen[Nc];
    #pragma unroll
    for (int n = 0; n < Nc; n++) Aen[n] = -__expf(Alog[e * Nc + n]);
    float wdt[Rc];
    #pragma unroll
    for (int r = 0; r < Rc; r++) wdt[r] = Wdt[r * Ec + e];
    float bd = bdt[e];
    float h[Nc];
    size_t o = ((size_t)blk * Ec + e) * Nc;
    #pragma unroll
    for (int n = 0; n < Nc; n++) h[n] = Hinit[o + n];
    float dp = Dpv[e];
    for (int t = 0; t < Tc; t++) {
        int row = base_row + t;
        float s = bd;
        #pragma unroll
        for (int r = 0; r < Rc; r++) s += Dsh[t][r] * wdt[r];
        float dtv = softplusf(s);
        float xv = xconv[(size_t)row * Ec + e];
        float dx = dtv * xv;
        float acc = 0.f;
        #pragma unroll
        for (int n = 0; n < Nc; n++) {
            float dA = __expf(dtv * Aen[n]);
            h[n] = dA * h[n] + dx * Bsh[t][n];
            acc += h[n] * Csh[t][n];
        }
        float yv = acc + dp * xv;
        float zv = xz[(size_t)row * 512 + 256 + e];
        float sig = 1.f / (1.f + __expf(-zv));
        xz[(size_t)row * 512 + e] = yv * (zv * sig);
    }
}

// ---------------------------------------------------------------------------
extern "C" void kernel_launch(void* const* d_in, const int* in_sizes, int n_in,
                              void* d_out, int out_size, void* d_ws, size_t ws_size,
                              hipStream_t stream) {
    const float* x        = (const float*)d_in[0];
    const float* bn_gamma = (const float*)d_in[1];
    const float* bn_beta  = (const float*)d_in[2];
    const float* ln_gamma = (const float*)d_in[3];
    const float* ln_beta  = (const float*)d_in[4];
    const float* W_in     = (const float*)d_in[5];
    const float* conv_w   = (const float*)d_in[6];
    const float* conv_b   = (const float*)d_in[7];
    const float* W_xp     = (const float*)d_in[8];
    const float* W_dt     = (const float*)d_in[9];
    const float* b_dt     = (const float*)d_in[10];
    const float* A_log    = (const float*)d_in[11];
    const float* Dp       = (const float*)d_in[12];
    const float* W_out    = (const float*)d_in[13];
    float* out = (float*)d_out;

    char* ws = (char*)d_ws;
    size_t off = 0;
    auto alloc = [&](size_t nbytes) {
        char* p = ws + off;
        off += ((nbytes + 255) / 256) * 256;
        return p;
    };
    float* xblc  = (float*)alloc((size_t)ROWS * Cc * 4);        // 8 MB
    float* buf2  = (float*)alloc((size_t)ROWS * Cc * 4);        // 8 MB
    float* u     = (float*)alloc((size_t)ROWS * Cc * 4);        // 8 MB
    float* xz    = (float*)alloc((size_t)ROWS * 512 * 4);       // 32 MB
    float* xconv = (float*)alloc((size_t)ROWS * Ec * 4);        // 16 MB
    float* dbl   = (float*)alloc((size_t)ROWS * 40 * 4);        // 2.6 MB
    float* P     = (float*)alloc((size_t)Bc * NCH * Ec * Nc * 4); // 33.5 MB
    float* F     = (float*)alloc((size_t)Bc * NCH * Ec * Nc * 4); // 33.5 MB
    float* part  = (float*)alloc(256 * 256 * 4);
    float* sums  = (float*)alloc(256 * 4);
    unsigned short* Wt_in  = (unsigned short*)alloc((size_t)2 * 512 * 128 * 2);
    unsigned short* Wt_xp  = (unsigned short*)alloc((size_t)2 * 64 * 256 * 2);
    unsigned short* Wt_out = (unsigned short*)alloc((size_t)2 * 128 * 256 * 2);

    transpose_in<<<dim3(Lc / 32, Cc / 32, Bc), dim3(32, 32), 0, stream>>>(x, xblc);
    // weight transpose+bf16 for both stages, up front
    wt_convert<<<(2 * 512 * 128) / 256, 256, 0, stream>>>(W_in,  Wt_in,  128, 512, 512);
    wt_convert<<<(2 * 64 * 256) / 256, 256, 0, stream>>>(W_xp,  Wt_xp,  256, 40, 64);
    wt_convert<<<(2 * 128 * 256) / 256, 256, 0, stream>>>(W_out, Wt_out, 256, 128, 128);

    for (int i = 0; i < 2; i++) {
        float* s_in  = (i == 0) ? xblc : buf2;
        float* s_out = (i == 0) ? buf2 : xblc;

        bn_stats_partial<<<256, 128, 0, stream>>>(s_in, part);
        bn_stats_final<<<1, 128, 0, stream>>>(part, sums);
        bn_ln<<<ROWS, 128, 0, stream>>>(s_in, sums,
                                        bn_gamma + i * Cc, bn_beta + i * Cc,
                                        ln_gamma + i * Cc, ln_beta + i * Cc,
                                        u, s_in /* un in place */);
        // xz = un @ W_in   (16384 x 512, K=128)
        mfma_gemm<128><<<dim3(8, ROWS / 64), 256, 0, stream>>>(
            s_in, Cc, Wt_in + (size_t)i * 512 * 128,
            nullptr, 0, xz, 512, 512);
        conv_silu<<<ROWS, Ec, 0, stream>>>(xz, conv_w + i * Ec * Kc, conv_b + i * Ec, xconv);
        // dbl = xconv @ W_xp  (16384 x 40, K=256)
        mfma_gemm<256><<<dim3(1, ROWS / 64), 256, 0, stream>>>(
            xconv, Ec, Wt_xp + (size_t)i * 64 * 256,
            nullptr, 0, dbl, 40, 40);
        scan_phase1<<<Bc * NCH, Ec, 0, stream>>>(xconv, dbl, A_log + i * Ec * Nc,
                                                 W_dt + i * Rc * Ec, b_dt + i * Ec, P, F);
        scan_phase2<<<Bc * Ec * Nc / 256, 256, 0, stream>>>(P, F);
        scan_phase3<<<Bc * NCH, Ec, 0, stream>>>(xconv, dbl, A_log + i * Ec * Nc,
                                                 W_dt + i * Rc * Ec, b_dt + i * Ec,
                                                 Dp + i * Ec, P /* Hinit */, xz);
        // s_out = u + y @ W_out  (16384 x 128, K=256); y lives in xz cols [0,256)
        mfma_gemm<256><<<dim3(2, ROWS / 64), 256, 0, stream>>>(
            xz, 512, Wt_out + (size_t)i * 128 * 256,
            u, Cc, s_out, Cc, 128);
    }

    final_out<<<dim3(Lc / 32, Cc / 32, Bc), dim3(32, 32), 0, stream>>>(xblc, x, out);
}

// Round 3
// 413.283 us; speedup vs baseline: 1.4606x; 1.2164x over previous
//
#include <hip/hip_runtime.h>
#include <math.h>

#define Bc 4
#define Cc 128
#define Lc 4096          // H*W
#define Ec 256
#define Nc 16
#define Rc 8
#define Kc 4
#define ROWS (Bc*Lc)     // 16384
#define EPSc 1e-5f
#define SLOPE 0.01f

#define NCH 128          // chunks per sequence
#define Tc 32            // chunk length (NCH*Tc == Lc)

typedef __attribute__((ext_vector_type(8))) short bf16x8;
typedef __attribute__((ext_vector_type(4))) float f32x4;

// RNE float->bf16, packed pair into one u32 (lo = x, hi = y)
__device__ inline unsigned pack_bf16_2(float x, float y) {
    unsigned bx = __float_as_uint(x);
    unsigned by = __float_as_uint(y);
    bx = (bx + 0x7FFFu + ((bx >> 16) & 1u)) >> 16;
    by = (by + 0x7FFFu + ((by >> 16) & 1u)) & 0xFFFF0000u;
    return bx | by;
}

__device__ inline float sigmoidf_fast(float s) {
    return 1.f / (1.f + __expf(-s));
}

__device__ inline float softplusf(float s) {
    return fmaxf(s, 0.f) + __logf(1.f + __expf(-fabsf(s)));
}

// ---------------------------------------------------------------------------
// Transpose x (B,C,L) -> xblc (B,L,C)
__global__ void transpose_in(const float* __restrict__ x, float* __restrict__ xblc) {
    __shared__ float tile[32][33];
    int b = blockIdx.z;
    int l0 = blockIdx.x * 32, c0 = blockIdx.y * 32;
    int tx = threadIdx.x, ty = threadIdx.y;
    tile[ty][tx] = x[((size_t)(b * Cc + c0 + ty)) * Lc + l0 + tx];
    __syncthreads();
    xblc[((size_t)(b * Lc + l0 + ty)) * Cc + c0 + tx] = tile[tx][ty];
}

// Final: out(B,C,L) = x(B,C,L) + s2(B,L,C) transposed
__global__ void final_out(const float* __restrict__ s2, const float* __restrict__ x,
                          float* __restrict__ out) {
    __shared__ float tile[32][33];
    int b = blockIdx.z;
    int l0 = blockIdx.x * 32, c0 = blockIdx.y * 32;
    int tx = threadIdx.x, ty = threadIdx.y;
    tile[ty][tx] = s2[((size_t)(b * Lc + l0 + ty)) * Cc + c0 + tx];
    __syncthreads();
    size_t oidx = ((size_t)(b * Cc + c0 + ty)) * Lc + l0 + tx;
    out[oidx] = x[oidx] + tile[tx][ty];
}

// ---------------------------------------------------------------------------
// Combined weight transpose+convert for all 3 weight tensors:
// W[2][K][N] fp32 -> Wt[2][NPAD][K] bf16 (zero-pad n)
__device__ inline void wt_one(const float* W, unsigned short* Wt, int idx,
                              int K, int N, int NPAD) {
    int k = idx % K;
    int n = (idx / K) % NPAD;
    int i = idx / (K * NPAD);
    float v = (n < N) ? W[(size_t)i * K * N + (size_t)k * N + n] : 0.f;
    unsigned b = __float_as_uint(v);
    Wt[idx] = (unsigned short)((b + 0x7FFFu + ((b >> 16) & 1u)) >> 16);
}

#define WT1 (2*512*128)
#define WT2 (2*64*256)
#define WT3 (2*128*256)
__global__ void wt_convert_all(const float* __restrict__ W_in, unsigned short* Wt_in,
                               const float* __restrict__ W_xp, unsigned short* Wt_xp,
                               const float* __restrict__ W_out, unsigned short* Wt_out) {
    int idx = blockIdx.x * 256 + threadIdx.x;
    if (idx < WT1) { wt_one(W_in, Wt_in, idx, 128, 512, 512); return; }
    idx -= WT1;
    if (idx < WT2) { wt_one(W_xp, Wt_xp, idx, 256, 40, 64); return; }
    idx -= WT2;
    if (idx < WT3) { wt_one(W_out, Wt_out, idx, 256, 128, 128); }
}

// ---------------------------------------------------------------------------
// BN stats: partial sums per 64-row slab, deterministic finalize
__global__ void bn_stats_partial(const float* __restrict__ xblc, float* __restrict__ part) {
    int c = threadIdx.x;              // 128
    int r0 = blockIdx.x * 64;         // 256 blocks
    float s = 0.f, s2 = 0.f;
    for (int r = 0; r < 64; r++) {
        float v = xblc[(size_t)(r0 + r) * Cc + c];
        s += v; s2 += v * v;
    }
    part[(size_t)blockIdx.x * 256 + c]       = s;
    part[(size_t)blockIdx.x * 256 + 128 + c] = s2;
}

__global__ void bn_stats_final(const float* __restrict__ part, float* __restrict__ sums) {
    int c = threadIdx.x;              // 128 threads, 1 block
    float s = 0.f, s2 = 0.f;
    for (int p = 0; p < 256; p++) {
        s  += part[(size_t)p * 256 + c];
        s2 += part[(size_t)p * 256 + 128 + c];
    }
    sums[c] = s;
    sums[128 + c] = s2;
}

// ---------------------------------------------------------------------------
// BN-normalize + leaky relu -> u ; LayerNorm -> un (in place over xin).
// One WAVE per row: 64 lanes x float2, shuffle reductions, no barriers.
__global__ __launch_bounds__(256) void bn_ln(
        const float* __restrict__ xin, const float* __restrict__ sums,
        const float* __restrict__ bng, const float* __restrict__ bnb,
        const float* __restrict__ lng, const float* __restrict__ lnb,
        float* __restrict__ u, float* __restrict__ un) {
    int wave = threadIdx.x >> 6, lane = threadIdx.x & 63;
    int row = blockIdx.x * 4 + wave;
    int c = lane * 2;
    float2 v = *(const float2*)(xin + (size_t)row * Cc + c);
    float2 sm = *(const float2*)(sums + c);
    float2 sq = *(const float2*)(sums + 128 + c);
    float2 g  = *(const float2*)(bng + c);
    float2 bt = *(const float2*)(bnb + c);
    const float inv = 1.f / (float)ROWS;
    float m0 = sm.x * inv, m1 = sm.y * inv;
    float va0 = sq.x * inv - m0 * m0, va1 = sq.y * inv - m1 * m1;
    float xn0 = (v.x - m0) * rsqrtf(va0 + EPSc) * g.x + bt.x;
    float xn1 = (v.y - m1) * rsqrtf(va1 + EPSc) * g.y + bt.y;
    xn0 = (xn0 < 0.f) ? SLOPE * xn0 : xn0;
    xn1 = (xn1 < 0.f) ? SLOPE * xn1 : xn1;
    float s = xn0 + xn1;
    float s2 = xn0 * xn0 + xn1 * xn1;
    #pragma unroll
    for (int m = 1; m < 64; m <<= 1) {
        s  += __shfl_xor(s, m, 64);
        s2 += __shfl_xor(s2, m, 64);
    }
    float m2 = s * (1.f / 128.f);
    float v2 = s2 * (1.f / 128.f) - m2 * m2;
    float rstd = rsqrtf(v2 + EPSc);
    float2 lg = *(const float2*)(lng + c);
    float2 lb = *(const float2*)(lnb + c);
    *(float2*)(u + (size_t)row * Cc + c) = make_float2(xn0, xn1);
    float2 o;
    o.x = (xn0 - m2) * rstd * lg.x + lb.x;
    o.y = (xn1 - m2) * rstd * lg.y + lb.y;
    *(float2*)(un + (size_t)row * Cc + c) = o;
}

// ---------------------------------------------------------------------------
// MFMA bf16 GEMM (LDS-free): Cout[M,N] = A[M,K](fp32) @ Wt[N][K](bf16)^T (+ add)
template<int K>
__global__ __launch_bounds__(256) void mfma_gemm(
        const float* __restrict__ A, int lda,
        const unsigned short* __restrict__ Wt,
        const float* __restrict__ add, int ldadd,
        float* __restrict__ Cout, int ldc, int N) {
    int tid = threadIdx.x;
    int wave = tid >> 6, lane = tid & 63;
    int quad = lane >> 4, l16 = lane & 15;
    int row0 = blockIdx.y * 64 + wave * 16;
    int col0 = blockIdx.x * 64;

    f32x4 acc[4] = {f32x4{0,0,0,0}, f32x4{0,0,0,0}, f32x4{0,0,0,0}, f32x4{0,0,0,0}};

    const float* arow = A + (size_t)(row0 + l16) * lda + quad * 8;
    const unsigned short* bbase = Wt + (size_t)(col0 + l16) * K + quad * 8;

    #pragma unroll
    for (int s = 0; s < K / 32; s++) {
        float4 a0 = *(const float4*)(arow + s * 32);
        float4 a1 = *(const float4*)(arow + s * 32 + 4);
        union { unsigned u[4]; bf16x8 v; } af;
        af.u[0] = pack_bf16_2(a0.x, a0.y);
        af.u[1] = pack_bf16_2(a0.z, a0.w);
        af.u[2] = pack_bf16_2(a1.x, a1.y);
        af.u[3] = pack_bf16_2(a1.z, a1.w);
        #pragma unroll
        for (int c = 0; c < 4; c++) {
            bf16x8 bf = *(const bf16x8*)(bbase + (size_t)c * 16 * K + s * 32);
            acc[c] = __builtin_amdgcn_mfma_f32_16x16x32_bf16(af.v, bf, acc[c], 0, 0, 0);
        }
    }

    #pragma unroll
    for (int c = 0; c < 4; c++) {
        int col = col0 + c * 16 + l16;
        if (col < N) {
            #pragma unroll
            for (int r = 0; r < 4; r++) {
                int row = row0 + quad * 4 + r;
                float v = acc[c][r];
                if (add) v += add[(size_t)row * ldadd + col];
                Cout[(size_t)row * ldc + col] = v;
            }
        }
    }
}

// ---------------------------------------------------------------------------
// depthwise causal conv (K=4) + bias + SiLU, 8 rows per block, sliding window.
// xz row stride 512, xm = cols [0,256)
__global__ __launch_bounds__(256) void conv_silu(
        const float* __restrict__ xz, const float* __restrict__ cw,
        const float* __restrict__ cb, float* __restrict__ xconv) {
    int r0 = blockIdx.x * 8;          // 2048 blocks; all 8 rows in same sequence
    int e = threadIdx.x;              // 256
    int l0 = r0 & (Lc - 1);
    float4 w = *(const float4*)(cw + e * 4);   // k=0..3, k=3 is current
    float bias = cb[e];
    float w0 = (l0 >= 3) ? xz[(size_t)(r0 - 3) * 512 + e] : 0.f;
    float w1 = (l0 >= 2) ? xz[(size_t)(r0 - 2) * 512 + e] : 0.f;
    float w2 = (l0 >= 1) ? xz[(size_t)(r0 - 1) * 512 + e] : 0.f;
    #pragma unroll
    for (int r = 0; r < 8; r++) {
        float cur = xz[(size_t)(r0 + r) * 512 + e];
        float s = bias + w0 * w.x + w1 * w.y + w2 * w.z + cur * w.w;
        xconv[(size_t)(r0 + r) * Ec + e] = s * sigmoidf_fast(s);
        w0 = w1; w1 = w2; w2 = cur;
    }
}

// ---------------------------------------------------------------------------
// Chunked selective scan, N split across lane pairs (8 states per thread).
// Block = 512 threads: tid -> e = tid>>1, half = tid&1; n = half*8 + j.
// PF layout: float2 {P,F} at ((blk*512 + tid)*8 + j); phase2 writes Hinit to .x
__global__ __launch_bounds__(512) void scan_phase1(
        const float* __restrict__ xconv, const float* __restrict__ dbl,
        const float* __restrict__ Alog,
        const float* __restrict__ Wdt, const float* __restrict__ bdt,
        float2* __restrict__ PF) {
    int blk = blockIdx.x;             // b*NCH + j
    int b = blk >> 7, j = blk & (NCH - 1);
    int tid = threadIdx.x;
    int e = tid >> 1, half = tid & 1;
    __shared__ float Bsh[Tc][Nc];
    __shared__ float Dsh[Tc][Rc];
    int base_row = b * Lc + j * Tc;
    for (int idx = tid; idx < Tc * Nc; idx += 512) {
        int t = idx >> 4, n = idx & 15;
        Bsh[t][n] = dbl[(size_t)(base_row + t) * 40 + 8 + n];
    }
    for (int idx = tid; idx < Tc * Rc; idx += 512) {
        int t = idx >> 3, r = idx & 7;
        Dsh[t][r] = dbl[(size_t)(base_row + t) * 40 + r];
    }
    __syncthreads();
    float Aen[8];
    #pragma unroll
    for (int n = 0; n < 8; n++) Aen[n] = -__expf(Alog[e * Nc + half * 8 + n]);
    float wdt[Rc];
    #pragma unroll
    for (int r = 0; r < Rc; r++) wdt[r] = Wdt[r * Ec + e];
    float bd = bdt[e];
    float Pv[8], Fv[8];
    #pragma unroll
    for (int n = 0; n < 8; n++) { Pv[n] = 1.f; Fv[n] = 0.f; }
    for (int t = 0; t < Tc; t++) {
        float s = bd;
        #pragma unroll
        for (int r = 0; r < Rc; r++) s += Dsh[t][r] * wdt[r];
        float dtv = softplusf(s);
        float xv = xconv[(size_t)(base_row + t) * Ec + e];
        float dx = dtv * xv;
        #pragma unroll
        for (int n = 0; n < 8; n++) {
            float dA = __expf(dtv * Aen[n]);
            Pv[n] *= dA;
            Fv[n] = dA * Fv[n] + dx * Bsh[t][half * 8 + n];
        }
    }
    size_t o = ((size_t)blk * 512 + tid) * 8;
    #pragma unroll
    for (int n = 0; n < 8; n++) PF[o + n] = make_float2(Pv[n], Fv[n]);
}

// phase2: affine scan across chunks; Hinit written over PF[].x
__global__ void scan_phase2(float2* PF) {
    int idx = blockIdx.x * blockDim.x + threadIdx.x;   // B*E*N = 16384
    int b = idx / (Ec * Nc);
    int r = idx % (Ec * Nc);
    float h = 0.f;
    for (int j = 0; j < NCH; j++) {
        size_t o = (size_t)(b * NCH + j) * (Ec * Nc) + r;
        float2 pf = PF[o];
        PF[o].x = h;            // Hinit
        h = pf.x * h + pf.y;
    }
}

// phase3: recompute in-chunk scan from Hinit, emit gated y into xz xm-region
__global__ __launch_bounds__(512) void scan_phase3(
        const float* __restrict__ xconv, const float* __restrict__ dbl,
        const float* __restrict__ Alog,
        const float* __restrict__ Wdt, const float* __restrict__ bdt,
        const float* __restrict__ Dpv, const float2* __restrict__ PF,
        float* xz) {
    int blk = blockIdx.x;
    int b = blk >> 7, j = blk & (NCH - 1);
    int tid = threadIdx.x;
    int e = tid >> 1, half = tid & 1;
    __shared__ float Bsh[Tc][Nc];
    __shared__ float Csh[Tc][Nc];
    __shared__ float Dsh[Tc][Rc];
    int base_row = b * Lc + j * Tc;
    for (int idx = tid; idx < Tc * Nc; idx += 512) {
        int t = idx >> 4, n = idx & 15;
        Bsh[t][n] = dbl[(size_t)(base_row + t) * 40 + 8 + n];
        Csh[t][n] = dbl[(size_t)(base_row + t) * 40 + 24 + n];
    }
    for (int idx = tid; idx < Tc * Rc; idx += 512) {
        int t = idx >> 3, r = idx & 7;
        Dsh[t][r] = dbl[(size_t)(base_row + t) * 40 + r];
    }
    __syncthreads();
    float Aen[8];
    #pragma unroll
    for (int n = 0; n < 8; n++) Aen[n] = -__expf(Alog[e * Nc + half * 8 + n]);
    float wdt[Rc];
    #pragma unroll
    for (int r = 0; r < Rc; r++) wdt[r] = Wdt[r * Ec + e];
    float bd = bdt[e];
    float h[8];
    size_t o = ((size_t)blk * 512 + tid) * 8;
    #pragma unroll
    for (int n = 0; n < 8; n++) h[n] = PF[o + n].x;
    float dp = Dpv[e];
    for (int t = 0; t < Tc; t++) {
        int row = base_row + t;
        float s = bd;
        #pragma unroll
        for (int r = 0; r < Rc; r++) s += Dsh[t][r] * wdt[r];
        float dtv = softplusf(s);
        float xv = xconv[(size_t)row * Ec + e];
        float dx = dtv * xv;
        float acc = 0.f;
        #pragma unroll
        for (int n = 0; n < 8; n++) {
            float dA = __expf(dtv * Aen[n]);
            h[n] = dA * h[n] + dx * Bsh[t][half * 8 + n];
            acc += h[n] * Csh[t][half * 8 + n];
        }
        acc += __shfl_xor(acc, 1, 64);
        if (half == 0) {
            float yv = acc + dp * xv;
            float zv = xz[(size_t)row * 512 + 256 + e];
            xz[(size_t)row * 512 + e] = yv * (zv * sigmoidf_fast(zv));
        }
    }
}

// ---------------------------------------------------------------------------
extern "C" void kernel_launch(void* const* d_in, const int* in_sizes, int n_in,
                              void* d_out, int out_size, void* d_ws, size_t ws_size,
                              hipStream_t stream) {
    const float* x        = (const float*)d_in[0];
    const float* bn_gamma = (const float*)d_in[1];
    const float* bn_beta  = (const float*)d_in[2];
    const float* ln_gamma = (const float*)d_in[3];
    const float* ln_beta  = (const float*)d_in[4];
    const float* W_in     = (const float*)d_in[5];
    const float* conv_w   = (const float*)d_in[6];
    const float* conv_b   = (const float*)d_in[7];
    const float* W_xp     = (const float*)d_in[8];
    const float* W_dt     = (const float*)d_in[9];
    const float* b_dt     = (const float*)d_in[10];
    const float* A_log    = (const float*)d_in[11];
    const float* Dp       = (const float*)d_in[12];
    const float* W_out    = (const float*)d_in[13];
    float* out = (float*)d_out;

    char* ws = (char*)d_ws;
    size_t off = 0;
    auto alloc = [&](size_t nbytes) {
        char* p = ws + off;
        off += ((nbytes + 255) / 256) * 256;
        return p;
    };
    float* xblc  = (float*)alloc((size_t)ROWS * Cc * 4);        // 8 MB (in-place both stages)
    float* u     = (float*)alloc((size_t)ROWS * Cc * 4);        // 8 MB
    float* xz    = (float*)alloc((size_t)ROWS * 512 * 4);       // 32 MB
    float* xconv = (float*)alloc((size_t)ROWS * Ec * 4);        // 16 MB
    float* dbl   = (float*)alloc((size_t)ROWS * 40 * 4);        // 2.6 MB
    float2* PF   = (float2*)alloc((size_t)Bc * NCH * Ec * Nc * 8); // 67 MB
    float* part  = (float*)alloc(256 * 256 * 4);
    float* sums  = (float*)alloc(256 * 4);
    unsigned short* Wt_in  = (unsigned short*)alloc((size_t)WT1 * 2);
    unsigned short* Wt_xp  = (unsigned short*)alloc((size_t)WT2 * 2);
    unsigned short* Wt_out = (unsigned short*)alloc((size_t)WT3 * 2);

    transpose_in<<<dim3(Lc / 32, Cc / 32, Bc), dim3(32, 32), 0, stream>>>(x, xblc);
    wt_convert_all<<<(WT1 + WT2 + WT3) / 256, 256, 0, stream>>>(
        W_in, Wt_in, W_xp, Wt_xp, W_out, Wt_out);

    for (int i = 0; i < 2; i++) {
        bn_stats_partial<<<256, 128, 0, stream>>>(xblc, part);
        bn_stats_final<<<1, 128, 0, stream>>>(part, sums);
        bn_ln<<<ROWS / 4, 256, 0, stream>>>(xblc, sums,
                                            bn_gamma + i * Cc, bn_beta + i * Cc,
                                            ln_gamma + i * Cc, ln_beta + i * Cc,
                                            u, xblc /* un in place */);
        // xz = un @ W_in   (16384 x 512, K=128)
        mfma_gemm<128><<<dim3(8, ROWS / 64), 256, 0, stream>>>(
            xblc, Cc, Wt_in + (size_t)i * 512 * 128,
            nullptr, 0, xz, 512, 512);
        conv_silu<<<ROWS / 8, 256, 0, stream>>>(xz, conv_w + i * Ec * Kc,
                                                conv_b + i * Ec, xconv);
        // dbl = xconv @ W_xp  (16384 x 40, K=256)
        mfma_gemm<256><<<dim3(1, ROWS / 64), 256, 0, stream>>>(
            xconv, Ec, Wt_xp + (size_t)i * 64 * 256,
            nullptr, 0, dbl, 40, 40);
        scan_phase1<<<Bc * NCH, 512, 0, stream>>>(xconv, dbl, A_log + i * Ec * Nc,
                                                  W_dt + i * Rc * Ec, b_dt + i * Ec, PF);
        scan_phase2<<<Bc * Ec * Nc / 256, 256, 0, stream>>>(PF);
        scan_phase3<<<Bc * NCH, 512, 0, stream>>>(xconv, dbl, A_log + i * Ec * Nc,
                                                  W_dt + i * Rc * Ec, b_dt + i * Ec,
                                                  Dp + i * Ec, PF, xz);
        // s_out = u + y @ W_out  (16384 x 128, K=256); y lives in xz cols [0,256)
        mfma_gemm<256><<<dim3(2, ROWS / 64), 256, 0, stream>>>(
            xz, 512, Wt_out + (size_t)i * 128 * 256,
            u, Cc, xblc, Cc, 128);
    }

    final_out<<<dim3(Lc / 32, Cc / 32, Bc), dim3(32, 32), 0, stream>>>(xblc, x, out);
}

// Round 4
// 399.267 us; speedup vs baseline: 1.5119x; 1.0351x over previous
//
#include <hip/hip_runtime.h>
#include <math.h>

#define Bc 4
#define Cc 128
#define Lc 4096          // H*W
#define Ec 256
#define Nc 16
#define Rc 8
#define Kc 4
#define ROWS (Bc*Lc)     // 16384
#define EPSc 1e-5f
#define SLOPE 0.01f

#define NCH 256          // chunks per sequence
#define Tc 16            // chunk length (NCH*Tc == Lc)

typedef __attribute__((ext_vector_type(8))) short bf16x8;
typedef __attribute__((ext_vector_type(4))) float f32x4;

// RNE float->bf16, packed pair into one u32 (lo = x, hi = y)
__device__ inline unsigned pack_bf16_2(float x, float y) {
    unsigned bx = __float_as_uint(x);
    unsigned by = __float_as_uint(y);
    bx = (bx + 0x7FFFu + ((bx >> 16) & 1u)) >> 16;
    by = (by + 0x7FFFu + ((by >> 16) & 1u)) & 0xFFFF0000u;
    return bx | by;
}

__device__ inline unsigned short to_bf16_rne(float x) {
    unsigned b = __float_as_uint(x);
    return (unsigned short)((b + 0x7FFFu + ((b >> 16) & 1u)) >> 16);
}

__device__ inline float sigmoidf_fast(float s) {
    return 1.f / (1.f + __expf(-s));
}

__device__ inline float softplusf(float s) {
    return fmaxf(s, 0.f) + __logf(1.f + __expf(-fabsf(s)));
}

// ---------------------------------------------------------------------------
// Transpose x (B,C,L) -> xblc (B,L,C)
__global__ void transpose_in(const float* __restrict__ x, float* __restrict__ xblc) {
    __shared__ float tile[32][33];
    int b = blockIdx.z;
    int l0 = blockIdx.x * 32, c0 = blockIdx.y * 32;
    int tx = threadIdx.x, ty = threadIdx.y;
    tile[ty][tx] = x[((size_t)(b * Cc + c0 + ty)) * Lc + l0 + tx];
    __syncthreads();
    xblc[((size_t)(b * Lc + l0 + ty)) * Cc + c0 + tx] = tile[tx][ty];
}

// Final: out(B,C,L) = x(B,C,L) + s2(B,L,C) transposed
__global__ void final_out(const float* __restrict__ s2, const float* __restrict__ x,
                          float* __restrict__ out) {
    __shared__ float tile[32][33];
    int b = blockIdx.z;
    int l0 = blockIdx.x * 32, c0 = blockIdx.y * 32;
    int tx = threadIdx.x, ty = threadIdx.y;
    tile[ty][tx] = s2[((size_t)(b * Lc + l0 + ty)) * Cc + c0 + tx];
    __syncthreads();
    size_t oidx = ((size_t)(b * Cc + c0 + ty)) * Lc + l0 + tx;
    out[oidx] = x[oidx] + tile[tx][ty];
}

// ---------------------------------------------------------------------------
// Combined weight transpose+convert: W[2][K][N] fp32 -> Wt[2][NPAD][K] bf16
__device__ inline void wt_one(const float* W, unsigned short* Wt, int idx,
                              int K, int N, int NPAD) {
    int k = idx % K;
    int n = (idx / K) % NPAD;
    int i = idx / (K * NPAD);
    float v = (n < N) ? W[(size_t)i * K * N + (size_t)k * N + n] : 0.f;
    Wt[idx] = to_bf16_rne(v);
}

#define WT1 (2*512*128)
#define WT2 (2*64*256)
#define WT3 (2*128*256)
__global__ void wt_convert_all(const float* __restrict__ W_in, unsigned short* Wt_in,
                               const float* __restrict__ W_xp, unsigned short* Wt_xp,
                               const float* __restrict__ W_out, unsigned short* Wt_out) {
    int idx = blockIdx.x * 256 + threadIdx.x;
    if (idx < WT1) { wt_one(W_in, Wt_in, idx, 128, 512, 512); return; }
    idx -= WT1;
    if (idx < WT2) { wt_one(W_xp, Wt_xp, idx, 256, 40, 64); return; }
    idx -= WT2;
    if (idx < WT3) { wt_one(W_out, Wt_out, idx, 256, 128, 128); }
}

// ---------------------------------------------------------------------------
// BN stats: partial sums per 64-row slab, deterministic finalize
__global__ void bn_stats_partial(const float* __restrict__ xblc, float* __restrict__ part) {
    int c = threadIdx.x;              // 128
    int r0 = blockIdx.x * 64;         // 256 blocks
    float s = 0.f, s2 = 0.f;
    for (int r = 0; r < 64; r++) {
        float v = xblc[(size_t)(r0 + r) * Cc + c];
        s += v; s2 += v * v;
    }
    part[(size_t)blockIdx.x * 256 + c]       = s;
    part[(size_t)blockIdx.x * 256 + 128 + c] = s2;
}

__global__ void bn_stats_final(const float* __restrict__ part, float* __restrict__ sums) {
    int c = threadIdx.x;              // 128 threads, 1 block
    float s = 0.f, s2 = 0.f;
    for (int p = 0; p < 256; p++) {
        s  += part[(size_t)p * 256 + c];
        s2 += part[(size_t)p * 256 + 128 + c];
    }
    sums[c] = s;
    sums[128 + c] = s2;
}

// ---------------------------------------------------------------------------
// BN-normalize + leaky relu -> u ; LayerNorm -> un (in place over xin).
// One WAVE per row: 64 lanes x float2, shuffle reductions, no barriers.
__global__ __launch_bounds__(256) void bn_ln(
        const float* __restrict__ xin, const float* __restrict__ sums,
        const float* __restrict__ bng, const float* __restrict__ bnb,
        const float* __restrict__ lng, const float* __restrict__ lnb,
        float* __restrict__ u, float* __restrict__ un) {
    int wave = threadIdx.x >> 6, lane = threadIdx.x & 63;
    int row = blockIdx.x * 4 + wave;
    int c = lane * 2;
    float2 v = *(const float2*)(xin + (size_t)row * Cc + c);
    float2 sm = *(const float2*)(sums + c);
    float2 sq = *(const float2*)(sums + 128 + c);
    float2 g  = *(const float2*)(bng + c);
    float2 bt = *(const float2*)(bnb + c);
    const float inv = 1.f / (float)ROWS;
    float m0 = sm.x * inv, m1 = sm.y * inv;
    float va0 = sq.x * inv - m0 * m0, va1 = sq.y * inv - m1 * m1;
    float xn0 = (v.x - m0) * rsqrtf(va0 + EPSc) * g.x + bt.x;
    float xn1 = (v.y - m1) * rsqrtf(va1 + EPSc) * g.y + bt.y;
    xn0 = (xn0 < 0.f) ? SLOPE * xn0 : xn0;
    xn1 = (xn1 < 0.f) ? SLOPE * xn1 : xn1;
    float s = xn0 + xn1;
    float s2 = xn0 * xn0 + xn1 * xn1;
    #pragma unroll
    for (int m = 1; m < 64; m <<= 1) {
        s  += __shfl_xor(s, m, 64);
        s2 += __shfl_xor(s2, m, 64);
    }
    float m2 = s * (1.f / 128.f);
    float v2 = s2 * (1.f / 128.f) - m2 * m2;
    float rstd = rsqrtf(v2 + EPSc);
    float2 lg = *(const float2*)(lng + c);
    float2 lb = *(const float2*)(lnb + c);
    *(float2*)(u + (size_t)row * Cc + c) = make_float2(xn0, xn1);
    float2 o;
    o.x = (xn0 - m2) * rstd * lg.x + lb.x;
    o.y = (xn1 - m2) * rstd * lg.y + lb.y;
    *(float2*)(un + (size_t)row * Cc + c) = o;
}

// ---------------------------------------------------------------------------
// MFMA bf16 GEMM (LDS-free): Cout[M,N] = A[M,K](fp32) @ Wt[N][K](bf16)^T
// Used for the in-projection only (N=512, K=128).
template<int K>
__global__ __launch_bounds__(256) void mfma_gemm(
        const float* __restrict__ A, int lda,
        const unsigned short* __restrict__ Wt,
        float* __restrict__ Cout, int ldc) {
    int tid = threadIdx.x;
    int wave = tid >> 6, lane = tid & 63;
    int quad = lane >> 4, l16 = lane & 15;
    int row0 = blockIdx.y * 64 + wave * 16;
    int col0 = blockIdx.x * 64;

    f32x4 acc[4] = {f32x4{0,0,0,0}, f32x4{0,0,0,0}, f32x4{0,0,0,0}, f32x4{0,0,0,0}};

    const float* arow = A + (size_t)(row0 + l16) * lda + quad * 8;
    const unsigned short* bbase = Wt + (size_t)(col0 + l16) * K + quad * 8;

    #pragma unroll
    for (int s = 0; s < K / 32; s++) {
        float4 a0 = *(const float4*)(arow + s * 32);
        float4 a1 = *(const float4*)(arow + s * 32 + 4);
        union { unsigned u[4]; bf16x8 v; } af;
        af.u[0] = pack_bf16_2(a0.x, a0.y);
        af.u[1] = pack_bf16_2(a0.z, a0.w);
        af.u[2] = pack_bf16_2(a1.x, a1.y);
        af.u[3] = pack_bf16_2(a1.z, a1.w);
        #pragma unroll
        for (int c = 0; c < 4; c++) {
            bf16x8 bf = *(const bf16x8*)(bbase + (size_t)c * 16 * K + s * 32);
            acc[c] = __builtin_amdgcn_mfma_f32_16x16x32_bf16(af.v, bf, acc[c], 0, 0, 0);
        }
    }

    #pragma unroll
    for (int c = 0; c < 4; c++) {
        int col = col0 + c * 16 + l16;
        #pragma unroll
        for (int r = 0; r < 4; r++) {
            int row = row0 + quad * 4 + r;
            Cout[(size_t)row * ldc + col] = acc[c][r];
        }
    }
}

// ---------------------------------------------------------------------------
// depthwise causal conv (K=4) + bias + SiLU, 8 rows per block, sliding window.
__global__ __launch_bounds__(256) void conv_silu(
        const float* __restrict__ xz, const float* __restrict__ cw,
        const float* __restrict__ cb, float* __restrict__ xconv) {
    int r0 = blockIdx.x * 8;          // 2048 blocks; all 8 rows in same sequence
    int e = threadIdx.x;              // 256
    int l0 = r0 & (Lc - 1);
    float4 w = *(const float4*)(cw + e * 4);
    float bias = cb[e];
    float w0 = (l0 >= 3) ? xz[(size_t)(r0 - 3) * 512 + e] : 0.f;
    float w1 = (l0 >= 2) ? xz[(size_t)(r0 - 2) * 512 + e] : 0.f;
    float w2 = (l0 >= 1) ? xz[(size_t)(r0 - 1) * 512 + e] : 0.f;
    #pragma unroll
    for (int r = 0; r < 8; r++) {
        float cur = xz[(size_t)(r0 + r) * 512 + e];
        float s = bias + w0 * w.x + w1 * w.y + w2 * w.z + cur * w.w;
        xconv[(size_t)(r0 + r) * Ec + e] = s * sigmoidf_fast(s);
        w0 = w1; w1 = w2; w2 = cur;
    }
}

// ---------------------------------------------------------------------------
// Fused x-proj GEMM + dt: dbl[64rows x 40] = xconv @ W_xp ; then
// dtb[64rows x 256] = softplus(dbl[:, :8] @ W_dt + b_dt)  (fp32 epilogue).
__global__ __launch_bounds__(256) void gemm_xp_dt(
        const float* __restrict__ xconv, const unsigned short* __restrict__ Wt_xp,
        const float* __restrict__ Wdt, const float* __restrict__ bdt,
        float* __restrict__ dbl, float* __restrict__ dtb) {
    __shared__ float d8[64][8];       // dt-input cols per row
    int tid = threadIdx.x;
    int wave = tid >> 6, lane = tid & 63;
    int quad = lane >> 4, l16 = lane & 15;
    int brow0 = blockIdx.x * 64;
    int row0 = brow0 + wave * 16;

    f32x4 acc[3] = {f32x4{0,0,0,0}, f32x4{0,0,0,0}, f32x4{0,0,0,0}};
    const float* arow = xconv + (size_t)(row0 + l16) * Ec + quad * 8;
    const unsigned short* bbase = Wt_xp + (size_t)l16 * Ec + quad * 8;

    #pragma unroll
    for (int s = 0; s < 8; s++) {
        float4 a0 = *(const float4*)(arow + s * 32);
        float4 a1 = *(const float4*)(arow + s * 32 + 4);
        union { unsigned u[4]; bf16x8 v; } af;
        af.u[0] = pack_bf16_2(a0.x, a0.y);
        af.u[1] = pack_bf16_2(a0.z, a0.w);
        af.u[2] = pack_bf16_2(a1.x, a1.y);
        af.u[3] = pack_bf16_2(a1.z, a1.w);
        #pragma unroll
        for (int c = 0; c < 3; c++) {
            bf16x8 bf = *(const bf16x8*)(bbase + (size_t)c * 16 * Ec + s * 32);
            acc[c] = __builtin_amdgcn_mfma_f32_16x16x32_bf16(af.v, bf, acc[c], 0, 0, 0);
        }
    }

    #pragma unroll
    for (int c = 0; c < 3; c++) {
        int col = c * 16 + l16;
        #pragma unroll
        for (int r = 0; r < 4; r++) {
            int row = row0 + quad * 4 + r;
            if (col < 40) dbl[(size_t)row * 40 + col] = acc[c][r];
        }
    }
    if (l16 < 8) {
        #pragma unroll
        for (int r = 0; r < 4; r++)
            d8[wave * 16 + quad * 4 + r][l16] = acc[0][r];
    }
    __syncthreads();

    // dt epilogue: thread = channel e, loop 64 rows (d8 reads are broadcasts)
    int e = tid;
    float wdt[Rc];
    #pragma unroll
    for (int r = 0; r < Rc; r++) wdt[r] = Wdt[r * Ec + e];
    float bd = bdt[e];
    for (int row = 0; row < 64; row++) {
        float s = bd;
        #pragma unroll
        for (int r = 0; r < Rc; r++) s += d8[row][r] * wdt[r];
        dtb[(size_t)(brow0 + row) * Ec + e] = softplusf(s);
    }
}

// ---------------------------------------------------------------------------
// Chunked selective scan, N split across lane pairs (8 states per thread).
// Block = 512 threads: tid -> e = tid>>1, half = tid&1.
// phase1: PF = {prod dA, from-zero final state}
__global__ __launch_bounds__(512) void scan_phase1(
        const float* __restrict__ xconv, const float* __restrict__ dbl,
        const float* __restrict__ dtb, const float* __restrict__ Alog,
        float2* __restrict__ PF) {
    int blk = blockIdx.x;             // b*NCH + j
    int b = blk >> 8, j = blk & (NCH - 1);
    int tid = threadIdx.x;
    int e = tid >> 1, half = tid & 1;
    __shared__ float Bsh[Tc][Nc];
    int base_row = b * Lc + j * Tc;
    if (tid < Tc * Nc) {
        int t = tid >> 4, n = tid & 15;
        Bsh[t][n] = dbl[(size_t)(base_row + t) * 40 + 8 + n];
    }
    __syncthreads();
    float Aen[8];
    #pragma unroll
    for (int n = 0; n < 8; n++) Aen[n] = -__expf(Alog[e * Nc + half * 8 + n]);
    float Pv[8], Fv[8];
    #pragma unroll
    for (int n = 0; n < 8; n++) { Pv[n] = 1.f; Fv[n] = 0.f; }
    #pragma unroll
    for (int t = 0; t < Tc; t++) {
        float dtv = dtb[(size_t)(base_row + t) * Ec + e];
        float xv  = xconv[(size_t)(base_row + t) * Ec + e];
        float dx = dtv * xv;
        #pragma unroll
        for (int n = 0; n < 8; n++) {
            float dA = __expf(dtv * Aen[n]);
            Pv[n] *= dA;
            Fv[n] = dA * Fv[n] + dx * Bsh[t][half * 8 + n];
        }
    }
    size_t o = ((size_t)blk * 512 + tid) * 8;
    #pragma unroll
    for (int n = 0; n < 8; n++) PF[o + n] = make_float2(Pv[n], Fv[n]);
}

// phase2: affine scan across chunks; Hinit written over PF[].x
__global__ void scan_phase2(float2* PF) {
    int idx = blockIdx.x * blockDim.x + threadIdx.x;   // B*E*N = 16384
    int b = idx / (Ec * Nc);
    int r = idx % (Ec * Nc);
    float h = 0.f;
    for (int j = 0; j < NCH; j++) {
        size_t o = (size_t)(b * NCH + j) * (Ec * Nc) + r;
        float2 pf = PF[o];
        PF[o].x = h;            // Hinit
        h = pf.x * h + pf.y;
    }
}

// phase3 + out-proj: recompute in-chunk scan from Hinit, gate with z, stage y
// as bf16 in LDS, then MFMA 16x128 out-tile = y @ W_out^T + u -> s_out.
__global__ __launch_bounds__(512) void scan_phase3_out(
        const float* __restrict__ xconv, const float* __restrict__ dbl,
        const float* __restrict__ dtb, const float* __restrict__ Alog,
        const float* __restrict__ Dpv, const float2* __restrict__ PF,
        const float* __restrict__ xz, const unsigned short* __restrict__ Wt_out,
        const float* __restrict__ u, float* __restrict__ s_out) {
    int blk = blockIdx.x;
    int b = blk >> 8, j = blk & (NCH - 1);
    int tid = threadIdx.x;
    int e = tid >> 1, half = tid & 1;
    __shared__ float Bsh[Tc][Nc];
    __shared__ float Csh[Tc][Nc];
    __shared__ unsigned short ytile[Tc][Ec + 8];   // +8 halves pad: 2-way max
    int base_row = b * Lc + j * Tc;
    if (tid < Tc * Nc) {
        int t = tid >> 4, n = tid & 15;
        Bsh[t][n] = dbl[(size_t)(base_row + t) * 40 + 8 + n];
    } else if (tid < 2 * Tc * Nc) {
        int k = tid - Tc * Nc;
        int t = k >> 4, n = k & 15;
        Csh[t][n] = dbl[(size_t)(base_row + t) * 40 + 24 + n];
    }
    __syncthreads();
    float Aen[8];
    #pragma unroll
    for (int n = 0; n < 8; n++) Aen[n] = -__expf(Alog[e * Nc + half * 8 + n]);
    float h[8];
    size_t o = ((size_t)blk * 512 + tid) * 8;
    #pragma unroll
    for (int n = 0; n < 8; n++) h[n] = PF[o + n].x;
    float dp = Dpv[e];
    #pragma unroll
    for (int t = 0; t < Tc; t++) {
        int row = base_row + t;
        float dtv = dtb[(size_t)row * Ec + e];
        float xv  = xconv[(size_t)row * Ec + e];
        float dx = dtv * xv;
        float acc = 0.f;
        #pragma unroll
        for (int n = 0; n < 8; n++) {
            float dA = __expf(dtv * Aen[n]);
            h[n] = dA * h[n] + dx * Bsh[t][half * 8 + n];
            acc += h[n] * Csh[t][half * 8 + n];
        }
        acc += __shfl_xor(acc, 1, 64);
        if (half == 0) {
            float yv = acc + dp * xv;
            float zv = xz[(size_t)row * 512 + 256 + e];
            ytile[t][e] = to_bf16_rne(yv * (zv * sigmoidf_fast(zv)));
        }
    }
    __syncthreads();

    // out-proj: 8 waves, wave w -> cols [w*16, w*16+16); K=256 in 8 steps
    int wave = tid >> 6, lane = tid & 63;
    int quad = lane >> 4, l16 = lane & 15;
    f32x4 acc = f32x4{0, 0, 0, 0};
    const unsigned short* bbase = Wt_out + (size_t)(wave * 16 + l16) * Ec + quad * 8;
    #pragma unroll
    for (int s = 0; s < 8; s++) {
        bf16x8 af = *(const bf16x8*)&ytile[l16][s * 32 + quad * 8];
        bf16x8 bf = *(const bf16x8*)(bbase + s * 32);
        acc = __builtin_amdgcn_mfma_f32_16x16x32_bf16(af, bf, acc, 0, 0, 0);
    }
    int col = wave * 16 + l16;
    #pragma unroll
    for (int r = 0; r < 4; r++) {
        int row = base_row + quad * 4 + r;
        s_out[(size_t)row * Cc + col] = acc[r] + u[(size_t)row * Cc + col];
    }
}

// ---------------------------------------------------------------------------
extern "C" void kernel_launch(void* const* d_in, const int* in_sizes, int n_in,
                              void* d_out, int out_size, void* d_ws, size_t ws_size,
                              hipStream_t stream) {
    const float* x        = (const float*)d_in[0];
    const float* bn_gamma = (const float*)d_in[1];
    const float* bn_beta  = (const float*)d_in[2];
    const float* ln_gamma = (const float*)d_in[3];
    const float* ln_beta  = (const float*)d_in[4];
    const float* W_in     = (const float*)d_in[5];
    const float* conv_w   = (const float*)d_in[6];
    const float* conv_b   = (const float*)d_in[7];
    const float* W_xp     = (const float*)d_in[8];
    const float* W_dt     = (const float*)d_in[9];
    const float* b_dt     = (const float*)d_in[10];
    const float* A_log    = (const float*)d_in[11];
    const float* Dp       = (const float*)d_in[12];
    const float* W_out    = (const float*)d_in[13];
    float* out = (float*)d_out;

    char* ws = (char*)d_ws;
    size_t off = 0;
    auto alloc = [&](size_t nbytes) {
        char* p = ws + off;
        off += ((nbytes + 255) / 256) * 256;
        return p;
    };
    float* xblc  = (float*)alloc((size_t)ROWS * Cc * 4);        // 8 MB (in-place both stages)
    float* u     = (float*)alloc((size_t)ROWS * Cc * 4);        // 8 MB
    float* xz    = (float*)alloc((size_t)ROWS * 512 * 4);       // 32 MB
    float* xconv = (float*)alloc((size_t)ROWS * Ec * 4);        // 16 MB
    float* dbl   = (float*)alloc((size_t)ROWS * 40 * 4);        // 2.6 MB
    float* dtb   = (float*)alloc((size_t)ROWS * Ec * 4);        // 16 MB
    float2* PF   = (float2*)alloc((size_t)Bc * NCH * Ec * Nc * 8); // 33.6 MB
    float* part  = (float*)alloc(256 * 256 * 4);
    float* sums  = (float*)alloc(256 * 4);
    unsigned short* Wt_in  = (unsigned short*)alloc((size_t)WT1 * 2);
    unsigned short* Wt_xp  = (unsigned short*)alloc((size_t)WT2 * 2);
    unsigned short* Wt_out = (unsigned short*)alloc((size_t)WT3 * 2);

    transpose_in<<<dim3(Lc / 32, Cc / 32, Bc), dim3(32, 32), 0, stream>>>(x, xblc);
    wt_convert_all<<<(WT1 + WT2 + WT3) / 256, 256, 0, stream>>>(
        W_in, Wt_in, W_xp, Wt_xp, W_out, Wt_out);

    for (int i = 0; i < 2; i++) {
        bn_stats_partial<<<256, 128, 0, stream>>>(xblc, part);
        bn_stats_final<<<1, 128, 0, stream>>>(part, sums);
        bn_ln<<<ROWS / 4, 256, 0, stream>>>(xblc, sums,
                                            bn_gamma + i * Cc, bn_beta + i * Cc,
                                            ln_gamma + i * Cc, ln_beta + i * Cc,
                                            u, xblc /* un in place */);
        // xz = un @ W_in   (16384 x 512, K=128)
        mfma_gemm<128><<<dim3(8, ROWS / 64), 256, 0, stream>>>(
            xblc, Cc, Wt_in + (size_t)i * 512 * 128, xz, 512);
        conv_silu<<<ROWS / 8, 256, 0, stream>>>(xz, conv_w + i * Ec * Kc,
                                                conv_b + i * Ec, xconv);
        // dbl = xconv @ W_xp (cols 0..40) + dtb = softplus(dbl8 @ W_dt + b)
        gemm_xp_dt<<<ROWS / 64, 256, 0, stream>>>(
            xconv, Wt_xp + (size_t)i * 64 * 256,
            W_dt + i * Rc * Ec, b_dt + i * Ec, dbl, dtb);
        scan_phase1<<<Bc * NCH, 512, 0, stream>>>(xconv, dbl, dtb,
                                                  A_log + i * Ec * Nc, PF);
        scan_phase2<<<Bc * Ec * Nc / 128, 128, 0, stream>>>(PF);
        scan_phase3_out<<<Bc * NCH, 512, 0, stream>>>(
            xconv, dbl, dtb, A_log + i * Ec * Nc, Dp + i * Ec, PF,
            xz, Wt_out + (size_t)i * 128 * 256, u, xblc);
    }

    final_out<<<dim3(Lc / 32, Cc / 32, Bc), dim3(32, 32), 0, stream>>>(xblc, x, out);
}

// Round 5
// 339.123 us; speedup vs baseline: 1.7801x; 1.1774x over previous
//
#include <hip/hip_runtime.h>
#include <math.h>

#define Bc 4
#define Cc 128
#define Lc 4096          // H*W
#define Ec 256
#define Nc 16
#define Rc 8
#define Kc 4
#define ROWS (Bc*Lc)     // 16384
#define EPSc 1e-5f
#define SLOPE 0.01f

#define NCH 128          // chunks per sequence
#define Tc 32            // chunk length (NCH*Tc == Lc)
#define SC 16            // super-chunks per sequence
#define SCL (NCH/SC)     // chunks per super-chunk = 8

typedef __attribute__((ext_vector_type(8))) short bf16x8;
typedef __attribute__((ext_vector_type(4))) float f32x4;

__device__ inline unsigned pack_bf16_2(float x, float y) {
    unsigned bx = __float_as_uint(x);
    unsigned by = __float_as_uint(y);
    bx = (bx + 0x7FFFu + ((bx >> 16) & 1u)) >> 16;
    by = (by + 0x7FFFu + ((by >> 16) & 1u)) & 0xFFFF0000u;
    return bx | by;
}
__device__ inline unsigned short to_bf16_rne(float x) {
    unsigned b = __float_as_uint(x);
    return (unsigned short)((b + 0x7FFFu + ((b >> 16) & 1u)) >> 16);
}
__device__ inline float bf16f(unsigned short u) {
    return __uint_as_float((unsigned)u << 16);
}
__device__ inline float sigmoidf_fast(float s) {
    return 1.f / (1.f + __expf(-s));
}
__device__ inline float softplusf(float s) {
    return fmaxf(s, 0.f) + __logf(1.f + __expf(-fabsf(s)));
}

// ---------------------------------------------------------------------------
// Transpose x (B,C,L) -> xblc (B,L,C)
__global__ void transpose_in(const float* __restrict__ x, float* __restrict__ xblc) {
    __shared__ float tile[32][33];
    int b = blockIdx.z;
    int l0 = blockIdx.x * 32, c0 = blockIdx.y * 32;
    int tx = threadIdx.x, ty = threadIdx.y;
    tile[ty][tx] = x[((size_t)(b * Cc + c0 + ty)) * Lc + l0 + tx];
    __syncthreads();
    xblc[((size_t)(b * Lc + l0 + ty)) * Cc + c0 + tx] = tile[tx][ty];
}

// ---------------------------------------------------------------------------
// Combined weight transpose+convert: W[2][K][N] fp32 -> Wt[2][NPAD][K] bf16
__device__ inline void wt_one(const float* W, unsigned short* Wt, int idx,
                              int K, int N, int NPAD) {
    int k = idx % K;
    int n = (idx / K) % NPAD;
    int i = idx / (K * NPAD);
    float v = (n < N) ? W[(size_t)i * K * N + (size_t)k * N + n] : 0.f;
    Wt[idx] = to_bf16_rne(v);
}
#define WT1 (2*512*128)
#define WT2 (2*64*256)
#define WT3 (2*128*256)
__global__ void wt_convert_all(const float* __restrict__ W_in, unsigned short* Wt_in,
                               const float* __restrict__ W_xp, unsigned short* Wt_xp,
                               const float* __restrict__ W_out, unsigned short* Wt_out) {
    int idx = blockIdx.x * 256 + threadIdx.x;
    if (idx < WT1) { wt_one(W_in, Wt_in, idx, 128, 512, 512); return; }
    idx -= WT1;
    if (idx < WT2) { wt_one(W_xp, Wt_xp, idx, 256, 40, 64); return; }
    idx -= WT2;
    if (idx < WT3) { wt_one(W_out, Wt_out, idx, 256, 128, 128); }
}

// ---------------------------------------------------------------------------
// BN stats
__global__ void bn_stats_partial(const float* __restrict__ xblc, float* __restrict__ part) {
    int c = threadIdx.x;              // 128
    int r0 = blockIdx.x * 64;         // 256 blocks
    float s = 0.f, s2 = 0.f;
    for (int r = 0; r < 64; r++) {
        float v = xblc[(size_t)(r0 + r) * Cc + c];
        s += v; s2 += v * v;
    }
    part[(size_t)blockIdx.x * 256 + c]       = s;
    part[(size_t)blockIdx.x * 256 + 128 + c] = s2;
}
__global__ void bn_stats_final(const float* __restrict__ part, float* __restrict__ sums) {
    int c = threadIdx.x;
    float s = 0.f, s2 = 0.f;
    for (int p = 0; p < 256; p++) {
        s  += part[(size_t)p * 256 + c];
        s2 += part[(size_t)p * 256 + 128 + c];
    }
    sums[c] = s;
    sums[128 + c] = s2;
}

// ---------------------------------------------------------------------------
// BN-normalize + leaky relu + LayerNorm -> un (xblc preserved).
__global__ __launch_bounds__(256) void bn_ln(
        const float* __restrict__ xin, const float* __restrict__ sums,
        const float* __restrict__ bng, const float* __restrict__ bnb,
        const float* __restrict__ lng, const float* __restrict__ lnb,
        float* __restrict__ un) {
    int wave = threadIdx.x >> 6, lane = threadIdx.x & 63;
    int row = blockIdx.x * 4 + wave;
    int c = lane * 2;
    float2 v = *(const float2*)(xin + (size_t)row * Cc + c);
    float2 sm = *(const float2*)(sums + c);
    float2 sq = *(const float2*)(sums + 128 + c);
    float2 g  = *(const float2*)(bng + c);
    float2 bt = *(const float2*)(bnb + c);
    const float inv = 1.f / (float)ROWS;
    float m0 = sm.x * inv, m1 = sm.y * inv;
    float va0 = sq.x * inv - m0 * m0, va1 = sq.y * inv - m1 * m1;
    float xn0 = (v.x - m0) * rsqrtf(va0 + EPSc) * g.x + bt.x;
    float xn1 = (v.y - m1) * rsqrtf(va1 + EPSc) * g.y + bt.y;
    xn0 = (xn0 < 0.f) ? SLOPE * xn0 : xn0;
    xn1 = (xn1 < 0.f) ? SLOPE * xn1 : xn1;
    float s = xn0 + xn1;
    float s2 = xn0 * xn0 + xn1 * xn1;
    #pragma unroll
    for (int m = 1; m < 64; m <<= 1) {
        s  += __shfl_xor(s, m, 64);
        s2 += __shfl_xor(s2, m, 64);
    }
    float m2 = s * (1.f / 128.f);
    float v2 = s2 * (1.f / 128.f) - m2 * m2;
    float rstd = rsqrtf(v2 + EPSc);
    float2 lg = *(const float2*)(lng + c);
    float2 lb = *(const float2*)(lnb + c);
    float2 o;
    o.x = (xn0 - m2) * rstd * lg.x + lb.x;
    o.y = (xn1 - m2) * rstd * lg.y + lb.y;
    *(float2*)(un + (size_t)row * Cc + c) = o;
}

// ---------------------------------------------------------------------------
// MEGA-FUSED middle: per 32-row tile (512 blocks, 256 thr / 4 waves):
//   in-proj GEMM (un@W_in -> xm LDS bf16, z global bf16)  [16-row halo recomputed]
//   depthwise conv K=4 + SiLU (in-place per column)       -> xcb global bf16
//   xp GEMM (xconv@W_xp -> dbl fp32)                      + dt epilogue -> dtb bf16
__global__ __launch_bounds__(256) void fused_mid(
        const float* __restrict__ un,
        const unsigned short* __restrict__ Wt_in,   // [512][128]
        const float* __restrict__ cw, const float* __restrict__ cb,
        const unsigned short* __restrict__ Wt_xp,   // [64][256]
        const float* __restrict__ Wdt, const float* __restrict__ bdt,
        unsigned short* __restrict__ zbuf,          // [ROWS][256] bf16
        unsigned short* __restrict__ xcb,           // [ROWS][256] bf16
        float* __restrict__ dbl,                    // [ROWS][40]
        unsigned short* __restrict__ dtb) {         // [ROWS][256] bf16
    __shared__ unsigned short xmtile[32][Ec + 8];
    __shared__ unsigned short xmprev[3][Ec];
    __shared__ float d8[32][8];
    int tid = threadIdx.x;
    int wave = tid >> 6, lane = tid & 63;
    int quad = lane >> 4, l16 = lane & 15;
    int r0 = blockIdx.x * 32;
    int l0 = r0 & (Lc - 1);
    int wt = wave >> 1;           // row-tile 0/1
    int ch = wave & 1;            // col-half: 0 -> xm cols, 1 -> z cols

    // ---- stage A: in-proj GEMM ----
    {
        // halo tile (rows r0-16..r0-1, xm cols): wave w covers col-tiles w*4..w*4+3
        if (l0 != 0) {
            const float* hrow = un + (size_t)(r0 - 16 + l16) * Cc + quad * 8;
            bf16x8 hf[4];
            #pragma unroll
            for (int s = 0; s < 4; s++) {
                float4 a0 = *(const float4*)(hrow + s * 32);
                float4 a1 = *(const float4*)(hrow + s * 32 + 4);
                union { unsigned u[4]; bf16x8 v; } t;
                t.u[0] = pack_bf16_2(a0.x, a0.y);
                t.u[1] = pack_bf16_2(a0.z, a0.w);
                t.u[2] = pack_bf16_2(a1.x, a1.y);
                t.u[3] = pack_bf16_2(a1.z, a1.w);
                hf[s] = t.v;
            }
            #pragma unroll
            for (int c = 0; c < 4; c++) {
                int ct = wave * 4 + c;
                f32x4 acc = f32x4{0, 0, 0, 0};
                const unsigned short* bb = Wt_in + (size_t)(ct * 16 + l16) * Cc + quad * 8;
                #pragma unroll
                for (int s = 0; s < 4; s++)
                    acc = __builtin_amdgcn_mfma_f32_16x16x32_bf16(
                        hf[s], *(const bf16x8*)(bb + s * 32), acc, 0, 0, 0);
                #pragma unroll
                for (int r = 0; r < 4; r++) {
                    int rr = quad * 4 + r;
                    if (rr >= 13) xmprev[rr - 13][ct * 16 + l16] = to_bf16_rne(acc[r]);
                }
            }
        } else {
            for (int idx = tid; idx < 3 * Ec; idx += 256)
                xmprev[idx / Ec][idx % Ec] = 0;
        }
        // main: wave (wt,ch): rows wt*16..+15, col-tiles ch*16..ch*16+15
        const float* arow = un + (size_t)(r0 + wt * 16 + l16) * Cc + quad * 8;
        bf16x8 af[4];
        #pragma unroll
        for (int s = 0; s < 4; s++) {
            float4 a0 = *(const float4*)(arow + s * 32);
            float4 a1 = *(const float4*)(arow + s * 32 + 4);
            union { unsigned u[4]; bf16x8 v; } t;
            t.u[0] = pack_bf16_2(a0.x, a0.y);
            t.u[1] = pack_bf16_2(a0.z, a0.w);
            t.u[2] = pack_bf16_2(a1.x, a1.y);
            t.u[3] = pack_bf16_2(a1.z, a1.w);
            af[s] = t.v;
        }
        #pragma unroll 4
        for (int c = 0; c < 16; c++) {
            int ct = ch * 16 + c;
            f32x4 acc = f32x4{0, 0, 0, 0};
            const unsigned short* bb = Wt_in + (size_t)(ct * 16 + l16) * Cc + quad * 8;
            #pragma unroll
            for (int s = 0; s < 4; s++)
                acc = __builtin_amdgcn_mfma_f32_16x16x32_bf16(
                    af[s], *(const bf16x8*)(bb + s * 32), acc, 0, 0, 0);
            if (ch == 0) {
                #pragma unroll
                for (int r = 0; r < 4; r++)
                    xmtile[wt * 16 + quad * 4 + r][ct * 16 + l16] = to_bf16_rne(acc[r]);
            } else {
                #pragma unroll
                for (int r = 0; r < 4; r++)
                    zbuf[(size_t)(r0 + wt * 16 + quad * 4 + r) * Ec + c * 16 + l16] =
                        to_bf16_rne(acc[r]);
            }
        }
    }
    __syncthreads();

    // ---- stage B: conv + silu (thread = channel), in-place into xmtile ----
    {
        int e = tid;
        float4 w = *(const float4*)(cw + e * 4);
        float bias = cb[e];
        float w0 = bf16f(xmprev[0][e]);
        float w1 = bf16f(xmprev[1][e]);
        float w2 = bf16f(xmprev[2][e]);
        #pragma unroll 4
        for (int t = 0; t < 32; t++) {
            float cur = bf16f(xmtile[t][e]);
            float s = bias + w0 * w.x + w1 * w.y + w2 * w.z + cur * w.w;
            float xc = s * sigmoidf_fast(s);
            unsigned short xb = to_bf16_rne(xc);
            xmtile[t][e] = xb;
            xcb[(size_t)(r0 + t) * Ec + e] = xb;
            w0 = w1; w1 = w2; w2 = cur;
        }
    }
    __syncthreads();

    // ---- stage C: xp GEMM (32x40) from xmtile; waves 0,1 only ----
    if (wave < 2) {
        bf16x8 af[8];
        #pragma unroll
        for (int s = 0; s < 8; s++)
            af[s] = *(const bf16x8*)&xmtile[wave * 16 + l16][s * 32 + quad * 8];
        #pragma unroll
        for (int c = 0; c < 3; c++) {
            f32x4 acc = f32x4{0, 0, 0, 0};
            const unsigned short* bb = Wt_xp + (size_t)(c * 16 + l16) * Ec + quad * 8;
            #pragma unroll
            for (int s = 0; s < 8; s++)
                acc = __builtin_amdgcn_mfma_f32_16x16x32_bf16(
                    af[s], *(const bf16x8*)(bb + s * 32), acc, 0, 0, 0);
            int col = c * 16 + l16;
            #pragma unroll
            for (int r = 0; r < 4; r++) {
                int row = wave * 16 + quad * 4 + r;
                if (col < 40) dbl[(size_t)(r0 + row) * 40 + col] = acc[r];
                if (c == 0 && l16 < 8) d8[row][l16] = acc[r];
            }
        }
    }
    __syncthreads();

    // ---- stage D: dt epilogue ----
    {
        int e = tid;
        float wdt[Rc];
        #pragma unroll
        for (int r = 0; r < Rc; r++) wdt[r] = Wdt[r * Ec + e];
        float bd = bdt[e];
        #pragma unroll 4
        for (int row = 0; row < 32; row++) {
            float s = bd;
            #pragma unroll
            for (int r = 0; r < Rc; r++) s += d8[row][r] * wdt[r];
            dtb[(size_t)(r0 + row) * Ec + e] = to_bf16_rne(softplusf(s));
        }
    }
}

// ---------------------------------------------------------------------------
// Chunked selective scan (Tc=32). Block 512 thr: e = tid>>1, half = tid&1.
__global__ __launch_bounds__(512) void scan_phase1(
        const unsigned short* __restrict__ xcb, const float* __restrict__ dbl,
        const unsigned short* __restrict__ dtb, const float* __restrict__ Alog,
        float2* __restrict__ PF) {
    int blk = blockIdx.x;             // b*NCH + j
    int b = blk >> 7, j = blk & (NCH - 1);
    int tid = threadIdx.x;
    int e = tid >> 1, half = tid & 1;
    __shared__ float Bsh[Tc][Nc];
    int base_row = b * Lc + j * Tc;
    {
        int t = tid >> 4, n = tid & 15;     // 512 = 32*16 exact
        Bsh[t][n] = dbl[(size_t)(base_row + t) * 40 + 8 + n];
    }
    __syncthreads();
    float Aen[8];
    #pragma unroll
    for (int n = 0; n < 8; n++) Aen[n] = -__expf(Alog[e * Nc + half * 8 + n]);
    float Pv[8], Fv[8];
    #pragma unroll
    for (int n = 0; n < 8; n++) { Pv[n] = 1.f; Fv[n] = 0.f; }
    for (int t = 0; t < Tc; t++) {
        float dtv = bf16f(dtb[(size_t)(base_row + t) * Ec + e]);
        float xv  = bf16f(xcb[(size_t)(base_row + t) * Ec + e]);
        float dx = dtv * xv;
        #pragma unroll
        for (int n = 0; n < 8; n++) {
            float dA = __expf(dtv * Aen[n]);
            Pv[n] *= dA;
            Fv[n] = dA * Fv[n] + dx * Bsh[t][half * 8 + n];
        }
    }
    size_t o = ((size_t)blk << 12) + tid * 8;
    #pragma unroll
    for (int n = 0; n < 8; n++) PF[o + n] = make_float2(Pv[n], Fv[n]);
}

// phase2a: compose each super-chunk's 8 chunks -> PFS
__global__ void scan_phase2a(const float2* __restrict__ PF, float2* __restrict__ PFS) {
    int idx = blockIdx.x * 256 + threadIdx.x;   // B*SC*4096
    int r = idx & 4095;
    int sc = (idx >> 12) & (SC - 1);
    int b = idx >> 16;
    float Pt = 1.f, Ft = 0.f;
    #pragma unroll
    for (int jj = 0; jj < SCL; jj++) {
        int j = sc * SCL + jj;
        float2 pf = PF[((size_t)(b * NCH + j) << 12) + r];
        Ft = pf.x * Ft + pf.y;
        Pt = pf.x * Pt;
    }
    PFS[((size_t)(b * SC + sc) << 12) + r] = make_float2(Pt, Ft);
}

// phase2b: serial scan over the 16 super-chunks; entering state -> PFS[].x
__global__ void scan_phase2b(float2* PFS) {
    int idx = blockIdx.x * 256 + threadIdx.x;   // B*4096
    int r = idx & 4095;
    int b = idx >> 12;
    float h = 0.f;
    for (int sc = 0; sc < SC; sc++) {
        size_t o = ((size_t)(b * SC + sc) << 12) + r;
        float2 pf = PFS[o];
        PFS[o].x = h;
        h = pf.x * h + pf.y;
    }
}

// phase2c: propagate within super-chunk; entering state per chunk -> PF[].x
__global__ void scan_phase2c(float2* __restrict__ PF, const float2* __restrict__ PFS) {
    int idx = blockIdx.x * 256 + threadIdx.x;   // B*SC*4096
    int r = idx & 4095;
    int sc = (idx >> 12) & (SC - 1);
    int b = idx >> 16;
    float h = PFS[((size_t)(b * SC + sc) << 12) + r].x;
    #pragma unroll
    for (int jj = 0; jj < SCL; jj++) {
        int j = sc * SCL + jj;
        size_t o = ((size_t)(b * NCH + j) << 12) + r;
        float2 pf = PF[o];
        PF[o].x = h;
        h = pf.x * h + pf.y;
    }
}

// ---------------------------------------------------------------------------
// phase3 + out-proj (+ final transpose&residual for stage 2).
// u recomputed from xblc + BN params (u buffer eliminated).
template<int FINAL>
__global__ __launch_bounds__(512) void scan_phase3_out(
        const unsigned short* __restrict__ xcb, const float* __restrict__ dbl,
        const unsigned short* __restrict__ dtb, const float* __restrict__ Alog,
        const float* __restrict__ Dpv, const float2* __restrict__ PF,
        const unsigned short* __restrict__ zbuf,
        const unsigned short* __restrict__ Wt_out,
        const float* __restrict__ xblc, const float* __restrict__ sums,
        const float* __restrict__ bng, const float* __restrict__ bnb,
        const float* __restrict__ xorig, float* __restrict__ outp) {
    int blk = blockIdx.x;
    int b = blk >> 7, j = blk & (NCH - 1);
    int tid = threadIdx.x;
    int e = tid >> 1, half = tid & 1;
    __shared__ float Bsh[Tc][Nc];
    __shared__ float Csh[Tc][Nc];
    __shared__ unsigned short ytile[Tc][Ec + 8];
    int base_row = b * Lc + j * Tc;
    {
        int t = tid >> 4, n = tid & 15;
        Bsh[t][n] = dbl[(size_t)(base_row + t) * 40 + 8 + n];
        Csh[t][n] = dbl[(size_t)(base_row + t) * 40 + 24 + n];
    }
    __syncthreads();
    float Aen[8];
    #pragma unroll
    for (int n = 0; n < 8; n++) Aen[n] = -__expf(Alog[e * Nc + half * 8 + n]);
    float h[8];
    size_t o = ((size_t)blk << 12) + tid * 8;
    #pragma unroll
    for (int n = 0; n < 8; n++) h[n] = PF[o + n].x;
    float dp = Dpv[e];
    for (int t = 0; t < Tc; t++) {
        int row = base_row + t;
        float dtv = bf16f(dtb[(size_t)row * Ec + e]);
        float xv  = bf16f(xcb[(size_t)row * Ec + e]);
        float dx = dtv * xv;
        float acc = 0.f;
        #pragma unroll
        for (int n = 0; n < 8; n++) {
            float dA = __expf(dtv * Aen[n]);
            h[n] = dA * h[n] + dx * Bsh[t][half * 8 + n];
            acc += h[n] * Csh[t][half * 8 + n];
        }
        acc += __shfl_xor(acc, 1, 64);
        if (half == 0) {
            float yv = acc + dp * xv;
            float zv = bf16f(zbuf[(size_t)row * Ec + e]);
            ytile[t][e] = to_bf16_rne(yv * (zv * sigmoidf_fast(zv)));
        }
    }
    __syncthreads();

    // out-proj: 8 waves x 16 cols, 2 row-tiles of 16
    int wave = tid >> 6, lane = tid & 63;
    int quad = lane >> 4, l16 = lane & 15;
    int col = wave * 16 + l16;
    const unsigned short* bb = Wt_out + (size_t)col * Ec + quad * 8;
    const float inv = 1.f / (float)ROWS;
    float mean = sums[col] * inv;
    float var  = sums[128 + col] * inv - mean * mean;
    float rstdg = rsqrtf(var + EPSc) * bng[col];
    float bbeta = bnb[col];
    #pragma unroll
    for (int rt = 0; rt < 2; rt++) {
        f32x4 acc = f32x4{0, 0, 0, 0};
        #pragma unroll
        for (int s = 0; s < 8; s++) {
            bf16x8 af = *(const bf16x8*)&ytile[rt * 16 + l16][s * 32 + quad * 8];
            acc = __builtin_amdgcn_mfma_f32_16x16x32_bf16(
                af, *(const bf16x8*)(bb + s * 32), acc, 0, 0, 0);
        }
        int row0 = base_row + rt * 16 + quad * 4;
        if (FINAL) {
            int l = row0 & (Lc - 1);
            size_t tb = ((size_t)(b * Cc + col) << 12) + l;
            float4 xo = *(const float4*)(xorig + tb);
            float4 res;
            #pragma unroll
            for (int r = 0; r < 4; r++) {
                float xb = xblc[(size_t)(row0 + r) * Cc + col];
                float xn = (xb - mean) * rstdg + bbeta;
                float uv = (xn < 0.f) ? SLOPE * xn : xn;
                ((float*)&res)[r] = acc[r] + uv + ((const float*)&xo)[r];
            }
            *(float4*)(outp + tb) = res;
        } else {
            #pragma unroll
            for (int r = 0; r < 4; r++) {
                int row = row0 + r;
                float xb = xblc[(size_t)row * Cc + col];
                float xn = (xb - mean) * rstdg + bbeta;
                float uv = (xn < 0.f) ? SLOPE * xn : xn;
                outp[(size_t)row * Cc + col] = acc[r] + uv;
            }
        }
    }
}

// ---------------------------------------------------------------------------
extern "C" void kernel_launch(void* const* d_in, const int* in_sizes, int n_in,
                              void* d_out, int out_size, void* d_ws, size_t ws_size,
                              hipStream_t stream) {
    const float* x        = (const float*)d_in[0];
    const float* bn_gamma = (const float*)d_in[1];
    const float* bn_beta  = (const float*)d_in[2];
    const float* ln_gamma = (const float*)d_in[3];
    const float* ln_beta  = (const float*)d_in[4];
    const float* W_in     = (const float*)d_in[5];
    const float* conv_w   = (const float*)d_in[6];
    const float* conv_b   = (const float*)d_in[7];
    const float* W_xp     = (const float*)d_in[8];
    const float* W_dt     = (const float*)d_in[9];
    const float* b_dt     = (const float*)d_in[10];
    const float* A_log    = (const float*)d_in[11];
    const float* Dp       = (const float*)d_in[12];
    const float* W_out    = (const float*)d_in[13];
    float* out = (float*)d_out;

    char* ws = (char*)d_ws;
    size_t off = 0;
    auto alloc = [&](size_t nbytes) {
        char* p = ws + off;
        off += ((nbytes + 255) / 256) * 256;
        return p;
    };
    float* xblc = (float*)alloc((size_t)ROWS * Cc * 4);           // 8 MB (stage io, in-place)
    float* un   = (float*)alloc((size_t)ROWS * Cc * 4);           // 8 MB
    unsigned short* zbuf = (unsigned short*)alloc((size_t)ROWS * Ec * 2);  // 8 MB
    unsigned short* xcb  = (unsigned short*)alloc((size_t)ROWS * Ec * 2);  // 8 MB
    unsigned short* dtb  = (unsigned short*)alloc((size_t)ROWS * Ec * 2);  // 8 MB
    float* dbl  = (float*)alloc((size_t)ROWS * 40 * 4);           // 2.6 MB
    float2* PF  = (float2*)alloc((size_t)Bc * NCH * Ec * Nc * 8); // 16.8 MB
    float2* PFS = (float2*)alloc((size_t)Bc * SC * Ec * Nc * 8);  // 2.1 MB
    float* part = (float*)alloc(256 * 256 * 4);
    float* sums = (float*)alloc(256 * 4);
    unsigned short* Wt_in  = (unsigned short*)alloc((size_t)WT1 * 2);
    unsigned short* Wt_xp  = (unsigned short*)alloc((size_t)WT2 * 2);
    unsigned short* Wt_out = (unsigned short*)alloc((size_t)WT3 * 2);

    transpose_in<<<dim3(Lc / 32, Cc / 32, Bc), dim3(32, 32), 0, stream>>>(x, xblc);
    wt_convert_all<<<(WT1 + WT2 + WT3) / 256, 256, 0, stream>>>(
        W_in, Wt_in, W_xp, Wt_xp, W_out, Wt_out);

    for (int i = 0; i < 2; i++) {
        bn_stats_partial<<<256, 128, 0, stream>>>(xblc, part);
        bn_stats_final<<<1, 128, 0, stream>>>(part, sums);
        bn_ln<<<ROWS / 4, 256, 0, stream>>>(xblc, sums,
                                            bn_gamma + i * Cc, bn_beta + i * Cc,
                                            ln_gamma + i * Cc, ln_beta + i * Cc, un);
        fused_mid<<<ROWS / 32, 256, 0, stream>>>(
            un, Wt_in + (size_t)i * 512 * 128,
            conv_w + i * Ec * Kc, conv_b + i * Ec,
            Wt_xp + (size_t)i * 64 * 256,
            W_dt + i * Rc * Ec, b_dt + i * Ec,
            zbuf, xcb, dbl, dtb);
        scan_phase1<<<Bc * NCH, 512, 0, stream>>>(xcb, dbl, dtb,
                                                  A_log + i * Ec * Nc, PF);
        scan_phase2a<<<(Bc * SC * 4096) / 256, 256, 0, stream>>>(PF, PFS);
        scan_phase2b<<<(Bc * 4096) / 256, 256, 0, stream>>>(PFS);
        scan_phase2c<<<(Bc * SC * 4096) / 256, 256, 0, stream>>>(PF, PFS);
        if (i == 0) {
            scan_phase3_out<0><<<Bc * NCH, 512, 0, stream>>>(
                xcb, dbl, dtb, A_log + i * Ec * Nc, Dp + i * Ec, PF,
                zbuf, Wt_out + (size_t)i * 128 * 256,
                xblc, sums, bn_gamma + i * Cc, bn_beta + i * Cc,
                nullptr, xblc);
        } else {
            scan_phase3_out<1><<<Bc * NCH, 512, 0, stream>>>(
                xcb, dbl, dtb, A_log + i * Ec * Nc, Dp + i * Ec, PF,
                zbuf, Wt_out + (size_t)i * 128 * 256,
                xblc, sums, bn_gamma + i * Cc, bn_beta + i * Cc,
                x, out);
        }
    }
}

// Round 6
// 311.136 us; speedup vs baseline: 1.9402x; 1.0900x over previous
//
#include <hip/hip_runtime.h>
#include <math.h>

#define Bc 4
#define Cc 128
#define Lc 4096          // H*W
#define Ec 256
#define Nc 16
#define Rc 8
#define Kc 4
#define ROWS (Bc*Lc)     // 16384
#define EPSc 1e-5f
#define SLOPE 0.01f

#define NCH 128          // chunks per sequence
#define Tc 32            // chunk length (NCH*Tc == Lc); == fused_mid row tile
#define SC 16            // super-chunks per sequence
#define SCL (NCH/SC)     // chunks per super-chunk = 8

typedef __attribute__((ext_vector_type(8))) short bf16x8;
typedef __attribute__((ext_vector_type(4))) float f32x4;

__device__ inline unsigned pack_bf16_2(float x, float y) {
    unsigned bx = __float_as_uint(x);
    unsigned by = __float_as_uint(y);
    bx = (bx + 0x7FFFu + ((bx >> 16) & 1u)) >> 16;
    by = (by + 0x7FFFu + ((by >> 16) & 1u)) & 0xFFFF0000u;
    return bx | by;
}
__device__ inline unsigned short to_bf16_rne(float x) {
    unsigned b = __float_as_uint(x);
    return (unsigned short)((b + 0x7FFFu + ((b >> 16) & 1u)) >> 16);
}
__device__ inline float bf16f(unsigned short u) {
    return __uint_as_float((unsigned)u << 16);
}
__device__ inline float sigmoidf_fast(float s) {
    return 1.f / (1.f + __expf(-s));
}
__device__ inline float softplusf(float s) {
    return fmaxf(s, 0.f) + __logf(1.f + __expf(-fabsf(s)));
}

// ---------------------------------------------------------------------------
// Transpose x (B,C,L) -> xblc (B,L,C)
__global__ void transpose_in(const float* __restrict__ x, float* __restrict__ xblc) {
    __shared__ float tile[32][33];
    int b = blockIdx.z;
    int l0 = blockIdx.x * 32, c0 = blockIdx.y * 32;
    int tx = threadIdx.x, ty = threadIdx.y;
    tile[ty][tx] = x[((size_t)(b * Cc + c0 + ty)) * Lc + l0 + tx];
    __syncthreads();
    xblc[((size_t)(b * Lc + l0 + ty)) * Cc + c0 + tx] = tile[tx][ty];
}

// ---------------------------------------------------------------------------
// Combined weight transpose+convert: W[2][K][N] fp32 -> Wt[2][NPAD][K] bf16
__device__ inline void wt_one(const float* W, unsigned short* Wt, int idx,
                              int K, int N, int NPAD) {
    int k = idx % K;
    int n = (idx / K) % NPAD;
    int i = idx / (K * NPAD);
    float v = (n < N) ? W[(size_t)i * K * N + (size_t)k * N + n] : 0.f;
    Wt[idx] = to_bf16_rne(v);
}
#define WT1 (2*512*128)
#define WT2 (2*64*256)
#define WT3 (2*128*256)
__global__ void wt_convert_all(const float* __restrict__ W_in, unsigned short* Wt_in,
                               const float* __restrict__ W_xp, unsigned short* Wt_xp,
                               const float* __restrict__ W_out, unsigned short* Wt_out) {
    int idx = blockIdx.x * 256 + threadIdx.x;
    if (idx < WT1) { wt_one(W_in, Wt_in, idx, 128, 512, 512); return; }
    idx -= WT1;
    if (idx < WT2) { wt_one(W_xp, Wt_xp, idx, 256, 40, 64); return; }
    idx -= WT2;
    if (idx < WT3) { wt_one(W_out, Wt_out, idx, 256, 128, 128); }
}

// ---------------------------------------------------------------------------
// BN stats
__global__ void bn_stats_partial(const float* __restrict__ xblc, float* __restrict__ part) {
    int c = threadIdx.x;              // 128
    int r0 = blockIdx.x * 64;         // 256 blocks
    float s = 0.f, s2 = 0.f;
    for (int r = 0; r < 64; r++) {
        float v = xblc[(size_t)(r0 + r) * Cc + c];
        s += v; s2 += v * v;
    }
    part[(size_t)blockIdx.x * 256 + c]       = s;
    part[(size_t)blockIdx.x * 256 + 128 + c] = s2;
}
__global__ void bn_stats_final(const float* __restrict__ part, float* __restrict__ sums) {
    int c = threadIdx.x;
    float s = 0.f, s2 = 0.f;
    for (int p = 0; p < 256; p++) {
        s  += part[(size_t)p * 256 + c];
        s2 += part[(size_t)p * 256 + 128 + c];
    }
    sums[c] = s;
    sums[128 + c] = s2;
}

// ---------------------------------------------------------------------------
// BN-normalize + leaky relu + LayerNorm -> un (xblc preserved).
__global__ __launch_bounds__(256) void bn_ln(
        const float* __restrict__ xin, const float* __restrict__ sums,
        const float* __restrict__ bng, const float* __restrict__ bnb,
        const float* __restrict__ lng, const float* __restrict__ lnb,
        float* __restrict__ un) {
    int wave = threadIdx.x >> 6, lane = threadIdx.x & 63;
    int row = blockIdx.x * 4 + wave;
    int c = lane * 2;
    float2 v = *(const float2*)(xin + (size_t)row * Cc + c);
    float2 sm = *(const float2*)(sums + c);
    float2 sq = *(const float2*)(sums + 128 + c);
    float2 g  = *(const float2*)(bng + c);
    float2 bt = *(const float2*)(bnb + c);
    const float inv = 1.f / (float)ROWS;
    float m0 = sm.x * inv, m1 = sm.y * inv;
    float va0 = sq.x * inv - m0 * m0, va1 = sq.y * inv - m1 * m1;
    float xn0 = (v.x - m0) * rsqrtf(va0 + EPSc) * g.x + bt.x;
    float xn1 = (v.y - m1) * rsqrtf(va1 + EPSc) * g.y + bt.y;
    xn0 = (xn0 < 0.f) ? SLOPE * xn0 : xn0;
    xn1 = (xn1 < 0.f) ? SLOPE * xn1 : xn1;
    float s = xn0 + xn1;
    float s2 = xn0 * xn0 + xn1 * xn1;
    #pragma unroll
    for (int m = 1; m < 64; m <<= 1) {
        s  += __shfl_xor(s, m, 64);
        s2 += __shfl_xor(s2, m, 64);
    }
    float m2 = s * (1.f / 128.f);
    float v2 = s2 * (1.f / 128.f) - m2 * m2;
    float rstd = rsqrtf(v2 + EPSc);
    float2 lg = *(const float2*)(lng + c);
    float2 lb = *(const float2*)(lnb + c);
    float2 o;
    o.x = (xn0 - m2) * rstd * lg.x + lb.x;
    o.y = (xn1 - m2) * rstd * lg.y + lb.y;
    *(float2*)(un + (size_t)row * Cc + c) = o;
}

// ---------------------------------------------------------------------------
// MEGA-FUSED middle + local scan. One block = one 32-row scan chunk.
// 512 threads (8 waves):
//   A: in-proj GEMM (un@W_in): xm -> LDS bf16, z -> global bf16; 16-row halo
//   B: depthwise conv K=4 + SiLU in place in LDS
//   C: xp GEMM -> dbl (global + LDS)
//   D: dt = softplus(dbl8@W_dt+b) -> LDS + packed {dt,xc} -> global dtxc
//   E: local chunk scan (phase1) straight from LDS -> PF global
__global__ __launch_bounds__(512) void fused_mid(
        const float* __restrict__ un,
        const unsigned short* __restrict__ Wt_in,   // [512][128]
        const float* __restrict__ cw, const float* __restrict__ cb,
        const unsigned short* __restrict__ Wt_xp,   // [64][256]
        const float* __restrict__ Wdt, const float* __restrict__ bdt,
        const float* __restrict__ Alog,
        unsigned short* __restrict__ zbuf,          // [ROWS][256] bf16
        unsigned* __restrict__ dtxc,                // [ROWS][256] packed {dt lo, xc hi}
        float* __restrict__ dbl,                    // [ROWS][40]
        float2* __restrict__ PF) {
    __shared__ __align__(16) unsigned short xmtile[32][Ec + 8];
    __shared__ __align__(16) unsigned short dtt[32][Ec];
    __shared__ unsigned short xmprev[3][Ec];
    __shared__ float dblsh[32][40];
    __shared__ float d8[32][8];
    int tid = threadIdx.x;
    int wave = tid >> 6, lane = tid & 63;
    int quad = lane >> 4, l16 = lane & 15;
    int r0 = blockIdx.x * 32;
    int l0 = r0 & (Lc - 1);

    // ---- stage A: in-proj GEMM ----
    {
        int rt = wave >> 2;            // row-tile 0/1
        int cb4 = (wave & 3) * 8;      // col-tile base (0,8,16,24)
        const float* arow = un + (size_t)(r0 + rt * 16 + l16) * Cc + quad * 8;
        bf16x8 af[4];
        #pragma unroll
        for (int s = 0; s < 4; s++) {
            float4 a0 = *(const float4*)(arow + s * 32);
            float4 a1 = *(const float4*)(arow + s * 32 + 4);
            union { unsigned u[4]; bf16x8 v; } t;
            t.u[0] = pack_bf16_2(a0.x, a0.y);
            t.u[1] = pack_bf16_2(a0.z, a0.w);
            t.u[2] = pack_bf16_2(a1.x, a1.y);
            t.u[3] = pack_bf16_2(a1.z, a1.w);
            af[s] = t.v;
        }
        if (l0 != 0) {
            // halo rows r0-16..r0-1, xm col-tiles: wave covers 2w, 2w+1
            const float* hrow = un + (size_t)(r0 - 16 + l16) * Cc + quad * 8;
            bf16x8 hf[4];
            #pragma unroll
            for (int s = 0; s < 4; s++) {
                float4 a0 = *(const float4*)(hrow + s * 32);
                float4 a1 = *(const float4*)(hrow + s * 32 + 4);
                union { unsigned u[4]; bf16x8 v; } t;
                t.u[0] = pack_bf16_2(a0.x, a0.y);
                t.u[1] = pack_bf16_2(a0.z, a0.w);
                t.u[2] = pack_bf16_2(a1.x, a1.y);
                t.u[3] = pack_bf16_2(a1.z, a1.w);
                hf[s] = t.v;
            }
            #pragma unroll
            for (int c = 0; c < 2; c++) {
                int ct = wave * 2 + c;
                f32x4 acc = f32x4{0, 0, 0, 0};
                const unsigned short* bb = Wt_in + (size_t)(ct * 16 + l16) * Cc + quad * 8;
                #pragma unroll
                for (int s = 0; s < 4; s++)
                    acc = __builtin_amdgcn_mfma_f32_16x16x32_bf16(
                        hf[s], *(const bf16x8*)(bb + s * 32), acc, 0, 0, 0);
                #pragma unroll
                for (int r = 0; r < 4; r++) {
                    int rr = quad * 4 + r;
                    if (rr >= 13) xmprev[rr - 13][ct * 16 + l16] = to_bf16_rne(acc[r]);
                }
            }
        } else {
            for (int idx = tid; idx < 3 * Ec; idx += 512)
                xmprev[idx / Ec][idx % Ec] = 0;
        }
        #pragma unroll
        for (int c = 0; c < 8; c++) {
            int ct = cb4 + c;
            f32x4 acc = f32x4{0, 0, 0, 0};
            const unsigned short* bb = Wt_in + (size_t)(ct * 16 + l16) * Cc + quad * 8;
            #pragma unroll
            for (int s = 0; s < 4; s++)
                acc = __builtin_amdgcn_mfma_f32_16x16x32_bf16(
                    af[s], *(const bf16x8*)(bb + s * 32), acc, 0, 0, 0);
            if (ct < 16) {
                #pragma unroll
                for (int r = 0; r < 4; r++)
                    xmtile[rt * 16 + quad * 4 + r][ct * 16 + l16] = to_bf16_rne(acc[r]);
            } else {
                #pragma unroll
                for (int r = 0; r < 4; r++)
                    zbuf[(size_t)(r0 + rt * 16 + quad * 4 + r) * Ec +
                         (ct - 16) * 16 + l16] = to_bf16_rne(acc[r]);
            }
        }
    }
    __syncthreads();

    // ---- stage B: conv + silu, in place. thread = (e2, hh): rows hh*16..+15
    int e2 = tid & 255, hh = tid >> 8;
    {
        float pw0, pw1, pw2;
        if (hh == 0) {
            pw0 = bf16f(xmprev[0][e2]);
            pw1 = bf16f(xmprev[1][e2]);
            pw2 = bf16f(xmprev[2][e2]);
        } else {
            pw0 = bf16f(xmtile[13][e2]);
            pw1 = bf16f(xmtile[14][e2]);
            pw2 = bf16f(xmtile[15][e2]);
        }
        __syncthreads();            // pre-reads done before in-place writes
        float4 w = *(const float4*)(cw + e2 * 4);
        float bias = cb[e2];
        #pragma unroll 4
        for (int k = 0; k < 16; k++) {
            int t = hh * 16 + k;
            float cur = bf16f(xmtile[t][e2]);
            float s = bias + pw0 * w.x + pw1 * w.y + pw2 * w.z + cur * w.w;
            xmtile[t][e2] = to_bf16_rne(s * sigmoidf_fast(s));
            pw0 = pw1; pw1 = pw2; pw2 = cur;
        }
    }
    __syncthreads();

    // ---- stage C: xp GEMM (32x40), waves 0..5: (rt2 = w&1, ct2 = w>>1) ----
    if (wave < 6) {
        int rt2 = wave & 1, ct2 = wave >> 1;
        bf16x8 a2[8];
        #pragma unroll
        for (int s = 0; s < 8; s++)
            a2[s] = *(const bf16x8*)&xmtile[rt2 * 16 + l16][s * 32 + quad * 8];
        f32x4 acc = f32x4{0, 0, 0, 0};
        const unsigned short* bb = Wt_xp + (size_t)(ct2 * 16 + l16) * Ec + quad * 8;
        #pragma unroll
        for (int s = 0; s < 8; s++)
            acc = __builtin_amdgcn_mfma_f32_16x16x32_bf16(
                a2[s], *(const bf16x8*)(bb + s * 32), acc, 0, 0, 0);
        int col = ct2 * 16 + l16;
        #pragma unroll
        for (int r = 0; r < 4; r++) {
            int row = rt2 * 16 + quad * 4 + r;
            if (col < 40) {
                dblsh[row][col] = acc[r];
                dbl[(size_t)(r0 + row) * 40 + col] = acc[r];
            }
            if (ct2 == 0 && l16 < 8) d8[row][l16] = acc[r];
        }
    }
    __syncthreads();

    // ---- stage D: dt epilogue + packed dtxc global write ----
    {
        float wdt[Rc];
        #pragma unroll
        for (int r = 0; r < Rc; r++) wdt[r] = Wdt[r * Ec + e2];
        float bd = bdt[e2];
        #pragma unroll 4
        for (int k = 0; k < 16; k++) {
            int t = hh * 16 + k;
            float s = bd;
            #pragma unroll
            for (int r = 0; r < Rc; r++) s += d8[t][r] * wdt[r];
            unsigned short db = to_bf16_rne(softplusf(s));
            dtt[t][e2] = db;
            unsigned short xb = xmtile[t][e2];
            dtxc[(size_t)(r0 + t) * Ec + e2] = (unsigned)db | ((unsigned)xb << 16);
        }
    }
    __syncthreads();

    // ---- stage E: local chunk scan (phase1) from LDS ----
    {
        int e = tid >> 1, half = tid & 1;
        float Aen[8];
        #pragma unroll
        for (int n = 0; n < 8; n++) Aen[n] = -__expf(Alog[e * Nc + half * 8 + n]);
        float Pv[8], Fv[8];
        #pragma unroll
        for (int n = 0; n < 8; n++) { Pv[n] = 1.f; Fv[n] = 0.f; }
        for (int t = 0; t < Tc; t++) {
            float dtv = bf16f(dtt[t][e]);
            float xv  = bf16f(xmtile[t][e]);
            float dx = dtv * xv;
            #pragma unroll
            for (int n = 0; n < 8; n++) {
                float dA = __expf(dtv * Aen[n]);
                Pv[n] *= dA;
                Fv[n] = dA * Fv[n] + dx * dblsh[t][8 + half * 8 + n];
            }
        }
        size_t o = ((size_t)blockIdx.x << 12) + tid * 8;
        #pragma unroll
        for (int n = 0; n < 8; n++) PF[o + n] = make_float2(Pv[n], Fv[n]);
    }
}

// ---------------------------------------------------------------------------
// phase2a: compose each super-chunk's 8 chunks -> PFS
__global__ void scan_phase2a(const float2* __restrict__ PF, float2* __restrict__ PFS) {
    int idx = blockIdx.x * 256 + threadIdx.x;   // B*SC*4096
    int r = idx & 4095;
    int sc = (idx >> 12) & (SC - 1);
    int b = idx >> 16;
    float Pt = 1.f, Ft = 0.f;
    #pragma unroll
    for (int jj = 0; jj < SCL; jj++) {
        int j = sc * SCL + jj;
        float2 pf = PF[((size_t)(b * NCH + j) << 12) + r];
        Ft = pf.x * Ft + pf.y;
        Pt = pf.x * Pt;
    }
    PFS[((size_t)(b * SC + sc) << 12) + r] = make_float2(Pt, Ft);
}

// phase2b: serial scan over the 16 super-chunks; entering state -> PFS[].x
__global__ void scan_phase2b(float2* PFS) {
    int idx = blockIdx.x * 256 + threadIdx.x;   // B*4096
    int r = idx & 4095;
    int b = idx >> 12;
    float h = 0.f;
    for (int sc = 0; sc < SC; sc++) {
        size_t o = ((size_t)(b * SC + sc) << 12) + r;
        float2 pf = PFS[o];
        PFS[o].x = h;
        h = pf.x * h + pf.y;
    }
}

// phase2c: propagate within super-chunk; entering state per chunk -> PF[].x
__global__ void scan_phase2c(float2* __restrict__ PF, const float2* __restrict__ PFS) {
    int idx = blockIdx.x * 256 + threadIdx.x;   // B*SC*4096
    int r = idx & 4095;
    int sc = (idx >> 12) & (SC - 1);
    int b = idx >> 16;
    float h = PFS[((size_t)(b * SC + sc) << 12) + r].x;
    #pragma unroll
    for (int jj = 0; jj < SCL; jj++) {
        int j = sc * SCL + jj;
        size_t o = ((size_t)(b * NCH + j) << 12) + r;
        float2 pf = PF[o];
        PF[o].x = h;
        h = pf.x * h + pf.y;
    }
}

// ---------------------------------------------------------------------------
// phase3 + out-proj (+ final transpose&residual for stage 2).
// All scan streams staged in LDS; z gated in place (ytile == ztile).
template<int FINAL>
__global__ __launch_bounds__(512) void scan_phase3_out(
        const unsigned* __restrict__ dtxc, const float* __restrict__ dbl,
        const float* __restrict__ Alog,
        const float* __restrict__ Dpv, const float2* __restrict__ PF,
        const unsigned short* __restrict__ zbuf,
        const unsigned short* __restrict__ Wt_out,
        const float* __restrict__ xblc, const float* __restrict__ sums,
        const float* __restrict__ bng, const float* __restrict__ bnb,
        const float* __restrict__ xorig, float* __restrict__ outp) {
    __shared__ __align__(16) unsigned dtxc_sh[32][Ec];
    __shared__ __align__(16) unsigned short zytile[Tc][Ec + 8];
    __shared__ float Bsh[Tc][Nc];
    __shared__ float Csh[Tc][Nc];
    int blk = blockIdx.x;
    int b = blk >> 7, j = blk & (NCH - 1);
    int tid = threadIdx.x;
    int e = tid >> 1, half = tid & 1;
    int base_row = b * Lc + j * Tc;
    // cooperative coalesced preloads
    {
        const uint4* src = (const uint4*)(dtxc + (size_t)base_row * Ec);
        uint4* dst = (uint4*)&dtxc_sh[0][0];
        #pragma unroll
        for (int k = 0; k < 4; k++) dst[tid + k * 512] = src[tid + k * 512];
        const uint4* zsrc = (const uint4*)(zbuf + (size_t)base_row * Ec);
        #pragma unroll
        for (int k = 0; k < 2; k++) {
            int idx = tid + k * 512;
            int row = idx >> 5, c8 = idx & 31;
            *(uint4*)&zytile[row][c8 * 8] = zsrc[idx];
        }
        int t = tid >> 4, n = tid & 15;
        Bsh[t][n] = dbl[(size_t)(base_row + t) * 40 + 8 + n];
        Csh[t][n] = dbl[(size_t)(base_row + t) * 40 + 24 + n];
    }
    __syncthreads();
    float Aen[8];
    #pragma unroll
    for (int n = 0; n < 8; n++) Aen[n] = -__expf(Alog[e * Nc + half * 8 + n]);
    float h[8];
    size_t o = ((size_t)blk << 12) + tid * 8;
    #pragma unroll
    for (int n = 0; n < 8; n++) h[n] = PF[o + n].x;
    float dp = Dpv[e];
    for (int t = 0; t < Tc; t++) {
        unsigned pk = dtxc_sh[t][e];
        float dtv = __uint_as_float(pk << 16);
        float xv  = __uint_as_float(pk & 0xFFFF0000u);
        float dx = dtv * xv;
        float acc = 0.f;
        #pragma unroll
        for (int n = 0; n < 8; n++) {
            float dA = __expf(dtv * Aen[n]);
            h[n] = dA * h[n] + dx * Bsh[t][half * 8 + n];
            acc += h[n] * Csh[t][half * 8 + n];
        }
        acc += __shfl_xor(acc, 1, 64);
        if (half == 0) {
            float yv = acc + dp * xv;
            float zv = bf16f(zytile[t][e]);
            zytile[t][e] = to_bf16_rne(yv * (zv * sigmoidf_fast(zv)));
        }
    }
    __syncthreads();

    // out-proj: 8 waves x 16 cols, 2 row-tiles of 16; u recomputed from BN
    int wave = tid >> 6, lane = tid & 63;
    int quad = lane >> 4, l16 = lane & 15;
    int col = wave * 16 + l16;
    const unsigned short* bb = Wt_out + (size_t)col * Ec + quad * 8;
    const float inv = 1.f / (float)ROWS;
    float mean = sums[col] * inv;
    float var  = sums[128 + col] * inv - mean * mean;
    float rstdg = rsqrtf(var + EPSc) * bng[col];
    float bbeta = bnb[col];
    #pragma unroll
    for (int rt = 0; rt < 2; rt++) {
        f32x4 acc = f32x4{0, 0, 0, 0};
        #pragma unroll
        for (int s = 0; s < 8; s++) {
            bf16x8 af = *(const bf16x8*)&zytile[rt * 16 + l16][s * 32 + quad * 8];
            acc = __builtin_amdgcn_mfma_f32_16x16x32_bf16(
                af, *(const bf16x8*)(bb + s * 32), acc, 0, 0, 0);
        }
        int row0 = base_row + rt * 16 + quad * 4;
        if (FINAL) {
            int l = row0 & (Lc - 1);
            size_t tb = ((size_t)(b * Cc + col) << 12) + l;
            float4 xo = *(const float4*)(xorig + tb);
            float4 res;
            #pragma unroll
            for (int r = 0; r < 4; r++) {
                float xb = xblc[(size_t)(row0 + r) * Cc + col];
                float xn = (xb - mean) * rstdg + bbeta;
                float uv = (xn < 0.f) ? SLOPE * xn : xn;
                ((float*)&res)[r] = acc[r] + uv + ((const float*)&xo)[r];
            }
            *(float4*)(outp + tb) = res;
        } else {
            #pragma unroll
            for (int r = 0; r < 4; r++) {
                int row = row0 + r;
                float xb = xblc[(size_t)row * Cc + col];
                float xn = (xb - mean) * rstdg + bbeta;
                float uv = (xn < 0.f) ? SLOPE * xn : xn;
                outp[(size_t)row * Cc + col] = acc[r] + uv;
            }
        }
    }
}

// ---------------------------------------------------------------------------
extern "C" void kernel_launch(void* const* d_in, const int* in_sizes, int n_in,
                              void* d_out, int out_size, void* d_ws, size_t ws_size,
                              hipStream_t stream) {
    const float* x        = (const float*)d_in[0];
    const float* bn_gamma = (const float*)d_in[1];
    const float* bn_beta  = (const float*)d_in[2];
    const float* ln_gamma = (const float*)d_in[3];
    const float* ln_beta  = (const float*)d_in[4];
    const float* W_in     = (const float*)d_in[5];
    const float* conv_w   = (const float*)d_in[6];
    const float* conv_b   = (const float*)d_in[7];
    const float* W_xp     = (const float*)d_in[8];
    const float* W_dt     = (const float*)d_in[9];
    const float* b_dt     = (const float*)d_in[10];
    const float* A_log    = (const float*)d_in[11];
    const float* Dp       = (const float*)d_in[12];
    const float* W_out    = (const float*)d_in[13];
    float* out = (float*)d_out;

    char* ws = (char*)d_ws;
    size_t off = 0;
    auto alloc = [&](size_t nbytes) {
        char* p = ws + off;
        off += ((nbytes + 255) / 256) * 256;
        return p;
    };
    float* xblc = (float*)alloc((size_t)ROWS * Cc * 4);           // 8 MB (stage io, in-place)
    float* un   = (float*)alloc((size_t)ROWS * Cc * 4);           // 8 MB
    unsigned short* zbuf = (unsigned short*)alloc((size_t)ROWS * Ec * 2);  // 8 MB
    unsigned* dtxc = (unsigned*)alloc((size_t)ROWS * Ec * 4);     // 16 MB packed {dt,xc}
    float* dbl  = (float*)alloc((size_t)ROWS * 40 * 4);           // 2.6 MB
    float2* PF  = (float2*)alloc((size_t)Bc * NCH * Ec * Nc * 8); // 16.8 MB
    float2* PFS = (float2*)alloc((size_t)Bc * SC * Ec * Nc * 8);  // 2.1 MB
    float* part = (float*)alloc(256 * 256 * 4);
    float* sums = (float*)alloc(256 * 4);
    unsigned short* Wt_in  = (unsigned short*)alloc((size_t)WT1 * 2);
    unsigned short* Wt_xp  = (unsigned short*)alloc((size_t)WT2 * 2);
    unsigned short* Wt_out = (unsigned short*)alloc((size_t)WT3 * 2);

    transpose_in<<<dim3(Lc / 32, Cc / 32, Bc), dim3(32, 32), 0, stream>>>(x, xblc);
    wt_convert_all<<<(WT1 + WT2 + WT3) / 256, 256, 0, stream>>>(
        W_in, Wt_in, W_xp, Wt_xp, W_out, Wt_out);

    for (int i = 0; i < 2; i++) {
        bn_stats_partial<<<256, 128, 0, stream>>>(xblc, part);
        bn_stats_final<<<1, 128, 0, stream>>>(part, sums);
        bn_ln<<<ROWS / 4, 256, 0, stream>>>(xblc, sums,
                                            bn_gamma + i * Cc, bn_beta + i * Cc,
                                            ln_gamma + i * Cc, ln_beta + i * Cc, un);
        fused_mid<<<ROWS / 32, 512, 0, stream>>>(
            un, Wt_in + (size_t)i * 512 * 128,
            conv_w + i * Ec * Kc, conv_b + i * Ec,
            Wt_xp + (size_t)i * 64 * 256,
            W_dt + i * Rc * Ec, b_dt + i * Ec, A_log + i * Ec * Nc,
            zbuf, dtxc, dbl, PF);
        scan_phase2a<<<(Bc * SC * 4096) / 256, 256, 0, stream>>>(PF, PFS);
        scan_phase2b<<<(Bc * 4096) / 256, 256, 0, stream>>>(PFS);
        scan_phase2c<<<(Bc * SC * 4096) / 256, 256, 0, stream>>>(PF, PFS);
        if (i == 0) {
            scan_phase3_out<0><<<Bc * NCH, 512, 0, stream>>>(
                dtxc, dbl, A_log + i * Ec * Nc, Dp + i * Ec, PF,
                zbuf, Wt_out + (size_t)i * 128 * 256,
                xblc, sums, bn_gamma + i * Cc, bn_beta + i * Cc,
                nullptr, xblc);
        } else {
            scan_phase3_out<1><<<Bc * NCH, 512, 0, stream>>>(
                dtxc, dbl, A_log + i * Ec * Nc, Dp + i * Ec, PF,
                zbuf, Wt_out + (size_t)i * 128 * 256,
                xblc, sums, bn_gamma + i * Cc, bn_beta + i * Cc,
                x, out);
        }
    }
}